// Round 2
// baseline (7216.605 us; speedup 1.0000x reference)
//
#include <hip/hip_runtime.h>
#include <math.h>

namespace {

constexpr int TT  = 192;   // timesteps
constexpr int INp = 24;    // input features
constexpr int Hh  = 64;    // hidden
constexpr int Kk  = 20;    // spline knots
constexpr int NG  = 4 * Hh;      // 256 gates per layer
constexpr int BB  = 8;           // batch rows per block
constexpr int NBLK = 2048 / BB;  // 256 blocks
constexpr int NTHR = 512;        // 8 waves, 2/SIMD at 1 block/CU

__device__ __forceinline__ float sigmoidf_(float x) {
  return 1.0f / (1.0f + __expf(-x));
}
__device__ __forceinline__ float tanhf_(float x) {
  return 2.0f / (1.0f + __expf(-2.0f * x)) - 1.0f;
}
__device__ __forceinline__ float softplusf_(float x) {
  return fmaxf(x, 0.0f) + log1pf(__expf(-fabsf(x)));
}

// Split-K: thread pair (g, g+256) shares gate g.
//  layer0 (K=88): half0 = x[0..24) + h0[0..20)  (44 w)
//                 half1 = h0[20..64)            (44 w)
//  layer1 (K=128): half0 = h0[0..64) (w_ih1), half1 = h1[0..64) (w_hh1)
__global__ __launch_bounds__(NTHR, 2) void lstm_crps_kernel(
    const float* __restrict__ train,   // [2048,192,24]
    const float* __restrict__ labels,  // [2048,192]
    const float* __restrict__ w_ih0,   // [256,24]
    const float* __restrict__ w_hh0,   // [256,64]
    const float* __restrict__ b_ih0,   // [256]
    const float* __restrict__ b_hh0,   // [256]
    const float* __restrict__ w_ih1,   // [256,64]
    const float* __restrict__ w_hh1,   // [256,64]
    const float* __restrict__ b_ih1,   // [256]
    const float* __restrict__ b_hh1,   // [256]
    const float* __restrict__ w_b0,    // [1,128]
    const float* __restrict__ bb_b0,   // [1]
    const float* __restrict__ w_g,     // [20,128]
    const float* __restrict__ b_g,     // [20]
    float* __restrict__ partials)      // [NBLK]
{
  __shared__ __align__(16) float x_l[BB][INp];
  __shared__ __align__(16) float h0_l[BB][68];   // pad 68: proj reads conflict-free
  __shared__ __align__(16) float h1_l[BB][68];
  __shared__ __align__(16) float gates2[2][BB][NG];  // split-K partials
  __shared__ float bg_l[BB][22];                 // [0]=beta0, [1..20]=gamma
  __shared__ __align__(16) float wproj[21][132];
  __shared__ float pbias[21];
  __shared__ float labels_l[BB][TT];
  __shared__ float red_l[NTHR];

  const int tid  = (int)threadIdx.x;
  const int g    = tid & 255;   // gate row
  const int half = tid >> 8;    // k-split half
  const int r0   = (int)blockIdx.x * BB;

  // ---- per-thread split-K weights (statically indexed -> VGPRs) ----
  float w0[44], w1[64];
  float bias_l0 = 0.0f, bias_l1 = 0.0f;
  if (half == 0) {
    const float* p = w_ih0 + (size_t)g * INp;
#pragma unroll
    for (int k = 0; k < 24; ++k) w0[k] = p[k];
    const float* q = w_hh0 + (size_t)g * Hh;
#pragma unroll
    for (int k = 0; k < 20; ++k) w0[24 + k] = q[k];
    const float* r = w_ih1 + (size_t)g * Hh;
#pragma unroll
    for (int k = 0; k < 64; ++k) w1[k] = r[k];
    bias_l0 = b_ih0[g] + b_hh0[g];
    bias_l1 = b_ih1[g] + b_hh1[g];
  } else {
    const float* q = w_hh0 + (size_t)g * Hh + 20;
#pragma unroll
    for (int k = 0; k < 44; ++k) w0[k] = q[k];
    const float* r = w_hh1 + (size_t)g * Hh;
#pragma unroll
    for (int k = 0; k < 64; ++k) w1[k] = r[k];
  }

  // ---- projection weights -> LDS ----
  for (int i = tid; i < 21 * 128; i += NTHR) {
    int o = i >> 7, kk2 = i & 127;
    wproj[o][kk2] = (o == 0) ? w_b0[kk2] : w_g[(size_t)(o - 1) * 128 + kk2];
  }
  if (tid < 21) pbias[tid] = (tid == 0) ? bb_b0[0] : b_g[tid - 1];

  // ---- labels ----
  for (int i = tid; i < BB * TT; i += NTHR) {
    int r = i / TT, t = i % TT;
    labels_l[r][t] = labels[(size_t)(r0 + r) * TT + t];
  }
  // ---- zero hidden state ----
  for (int i = tid; i < BB * 68; i += NTHR) {
    (&h0_l[0][0])[i] = 0.0f;
    (&h1_l[0][0])[i] = 0.0f;
  }

  // cell-state: thread (row = tid>>6, feat = tid&63), one (c0,c1) pair each
  const int crow = tid >> 6;   // 0..7
  const int cf   = tid & 63;
  float c0 = 0.0f, c1 = 0.0f;

  // x prefetch
  const int xi_r = tid / INp, xi_k = tid % INp;
  float xr = 0.0f;
  if (tid < BB * INp) xr = train[((size_t)(r0 + xi_r) * TT + 0) * INp + xi_k];

  const float sig = 1.0f / (float)Kk;
  const int lcr = tid & 31;
  float myksi = 0.0f;
  for (int i = 0; i < lcr && i < Kk; ++i) myksi += sig;  // cumsum fidelity

  float cacc = 0.0f;

  __syncthreads();

  for (int t = 0; t < TT; ++t) {
    if (tid < BB * INp) x_l[xi_r][xi_k] = xr;
    __syncthreads();  // B1
    if (tid < BB * INp && (t + 1) < TT)
      xr = train[((size_t)(r0 + xi_r) * TT + (t + 1)) * INp + xi_k];

    float acc[BB];

    // ---- layer 0 gate partials ----
#pragma unroll
    for (int r = 0; r < BB; ++r) acc[r] = bias_l0;
    if (half == 0) {
#pragma unroll
      for (int kc = 0; kc < 6; ++kc) {
#pragma unroll
        for (int r = 0; r < BB; ++r) {
          float4 v = *reinterpret_cast<const float4*>(&x_l[r][kc * 4]);
          acc[r] += w0[kc * 4 + 0] * v.x + w0[kc * 4 + 1] * v.y +
                    w0[kc * 4 + 2] * v.z + w0[kc * 4 + 3] * v.w;
        }
      }
#pragma unroll
      for (int kc = 0; kc < 5; ++kc) {
#pragma unroll
        for (int r = 0; r < BB; ++r) {
          float4 v = *reinterpret_cast<const float4*>(&h0_l[r][kc * 4]);
          acc[r] += w0[24 + kc * 4 + 0] * v.x + w0[24 + kc * 4 + 1] * v.y +
                    w0[24 + kc * 4 + 2] * v.z + w0[24 + kc * 4 + 3] * v.w;
        }
      }
    } else {
#pragma unroll
      for (int kc = 0; kc < 11; ++kc) {
#pragma unroll
        for (int r = 0; r < BB; ++r) {
          float4 v = *reinterpret_cast<const float4*>(&h0_l[r][20 + kc * 4]);
          acc[r] += w0[kc * 4 + 0] * v.x + w0[kc * 4 + 1] * v.y +
                    w0[kc * 4 + 2] * v.z + w0[kc * 4 + 3] * v.w;
        }
      }
    }
#pragma unroll
    for (int r = 0; r < BB; ++r) gates2[half][r][g] = acc[r];
    __syncthreads();  // B2

    // ---- layer 0 cell update: thread (crow, cf) ----
    {
      float gi = gates2[0][crow][cf]       + gates2[1][crow][cf];
      float gf = gates2[0][crow][64 + cf]  + gates2[1][crow][64 + cf];
      float gg = gates2[0][crow][128 + cf] + gates2[1][crow][128 + cf];
      float go = gates2[0][crow][192 + cf] + gates2[1][crow][192 + cf];
      float c2 = sigmoidf_(gf) * c0 + sigmoidf_(gi) * tanhf_(gg);
      c0 = c2;
      h0_l[crow][cf] = sigmoidf_(go) * tanhf_(c2);
    }
    __syncthreads();  // B3

    // ---- layer 1 gate partials (half0: new h0 via w_ih1; half1: old h1 via w_hh1) ----
#pragma unroll
    for (int r = 0; r < BB; ++r) acc[r] = bias_l1;
    if (half == 0) {
#pragma unroll
      for (int kc = 0; kc < 16; ++kc) {
#pragma unroll
        for (int r = 0; r < BB; ++r) {
          float4 v = *reinterpret_cast<const float4*>(&h0_l[r][kc * 4]);
          acc[r] += w1[kc * 4 + 0] * v.x + w1[kc * 4 + 1] * v.y +
                    w1[kc * 4 + 2] * v.z + w1[kc * 4 + 3] * v.w;
        }
      }
    } else {
#pragma unroll
      for (int kc = 0; kc < 16; ++kc) {
#pragma unroll
        for (int r = 0; r < BB; ++r) {
          float4 v = *reinterpret_cast<const float4*>(&h1_l[r][kc * 4]);
          acc[r] += w1[kc * 4 + 0] * v.x + w1[kc * 4 + 1] * v.y +
                    w1[kc * 4 + 2] * v.z + w1[kc * 4 + 3] * v.w;
        }
      }
    }
#pragma unroll
    for (int r = 0; r < BB; ++r) gates2[half][r][g] = acc[r];
    __syncthreads();  // B4

    // ---- layer 1 cell update ----
    {
      float gi = gates2[0][crow][cf]       + gates2[1][crow][cf];
      float gf = gates2[0][crow][64 + cf]  + gates2[1][crow][64 + cf];
      float gg = gates2[0][crow][128 + cf] + gates2[1][crow][128 + cf];
      float go = gates2[0][crow][192 + cf] + gates2[1][crow][192 + cf];
      float c2 = sigmoidf_(gf) * c1 + sigmoidf_(gi) * tanhf_(gg);
      c1 = c2;
      h1_l[crow][cf] = sigmoidf_(go) * tanhf_(c2);
    }
    __syncthreads();  // B5

    // ---- projection + softplus: feats[b][2h+l] = h_l[b][h] ----
    if (tid < BB * 21) {
      int o = tid >> 3, r = tid & 7;
      float lin = pbias[o];
#pragma unroll 16
      for (int h = 0; h < Hh; ++h) {
        float2 wv = *reinterpret_cast<const float2*>(&wproj[o][2 * h]);
        lin += h0_l[r][h] * wv.x + h1_l[r][h] * wv.y;
      }
      bg_l[r][o] = softplusf_(lin);
    }
    __syncthreads();  // B6

    // ---- CRPS: one 32-lane group per row, first 256 threads ----
    if (tid < 256) {
      const int grp = tid >> 5;
      const int l = tid & 31;
      const bool valid = (l < Kk);
      const float y = labels_l[grp][t];
      const float b0v = bg_l[grp][0];

      float braw = 0.0f;
      if (valid) {
        float gam = bg_l[grp][1 + l];
        float bp  = bg_l[grp][l];
        braw = (gam - bp) / (2.0f * sig);
      }
      float brawm1 = __shfl_up(braw, 1, 32);
      float bj = valid ? (braw - ((l == 0) ? 0.0f : brawm1)) : 0.0f;
      float st = (l < Kk - 1) ? bj : 0.0f;
#pragma unroll
      for (int off = 16; off > 0; off >>= 1) st += __shfl_xor(st, off, 32);
      if (l == Kk - 1) bj = bg_l[grp][Kk] - st;

      float knot = b0v * myksi;
      float kj = 0.0f;
#pragma unroll
      for (int j = 0; j < Kk; ++j) {
        float bjj = __shfl(bj, j, 32);
        float d = fmaxf(myksi - kj, 0.0f);
        knot += bjj * d * d;
        kj += sig;
      }
      float diff = y - knot;
      bool al = valid && (diff > 0.0f);
      float ab = al ? bj : 0.0f;
      float tA = ab;
      float tB = ab * myksi;
      float tC = ab * myksi * myksi;
      float u = 1.0f - myksi;
      float c3t = valid ? (bj * (1.0f / 6.0f)) * (u * u * u * u) : 0.0f;
      float ad = valid ? fabsf(diff) : 3.4e38f;
      int ai = l;
#pragma unroll
      for (int off = 16; off > 0; off >>= 1) {
        tA += __shfl_xor(tA, off, 32);
        tB += __shfl_xor(tB, off, 32);
        tC += __shfl_xor(tC, off, 32);
        c3t += __shfl_xor(c3t, off, 32);
        float oad = __shfl_xor(ad, off, 32);
        int   oai = __shfl_xor(ai, off, 32);
        if (oad < ad || (oad == ad && oai < ai)) { ad = oad; ai = oai; }
      }
      float A   = tA;
      float Bco = b0v - 2.0f * tB;
      float Cc  = -y + tC;
      float disc = Bco * Bco - 4.0f * A * Cc;
      float ksi_pick = __shfl(myksi, ai, 32);
      float A_safe = (A != 0.0f) ? A : 1.0f;
      float B_safe = (Bco != 0.0f) ? Bco : 1.0f;
      float quad = (-Bco + sqrtf(fmaxf(disc, 0.0f))) / (2.0f * A_safe);
      float alpha = (A != 0.0f && disc >= 0.0f)
                        ? quad
                        : ((A == 0.0f) ? (-Cc / B_safe) : ksi_pick);
      float dk = alpha - myksi;
      float c4t = al ? ((2.0f / 3.0f) * bj) * (dk * dk * dk) : 0.0f;
#pragma unroll
      for (int off = 16; off > 0; off >>= 1) c4t += __shfl_xor(c4t, off, 32);
      float crps = y * (2.0f * alpha - 1.0f) +
                   b0v * ((1.0f / 3.0f) - alpha * alpha) + c3t - c4t;
      if (l == 0) cacc += crps;
    }
    // no barrier: next iter's x_l write doesn't alias CRPS/proj reads;
    // B1..B6 separate all other producer/consumer pairs across iterations
  }

  // ---- block reduction ----
  red_l[tid] = cacc;
  __syncthreads();
#pragma unroll
  for (int s = NTHR / 2; s > 0; s >>= 1) {
    if (tid < s) red_l[tid] += red_l[tid + s];
    __syncthreads();
  }
  if (tid == 0) partials[blockIdx.x] = red_l[0];
}

__global__ void final_reduce_kernel(const float* __restrict__ partials,
                                    float* __restrict__ out) {
  __shared__ float s_l[NBLK];
  const int tid = (int)threadIdx.x;
  s_l[tid] = partials[tid];
  __syncthreads();
  for (int s = NBLK / 2; s > 0; s >>= 1) {
    if (tid < s) s_l[tid] += s_l[tid + s];
    __syncthreads();
  }
  if (tid == 0) out[0] = s_l[0] * (1.0f / 2048.0f);
}

}  // namespace

extern "C" void kernel_launch(void* const* d_in, const int* in_sizes, int n_in,
                              void* d_out, int out_size, void* d_ws, size_t ws_size,
                              hipStream_t stream) {
  (void)in_sizes; (void)n_in; (void)out_size; (void)ws_size;
  const float* train  = (const float*)d_in[0];
  const float* labels = (const float*)d_in[1];
  const float* w_ih0  = (const float*)d_in[2];
  const float* w_hh0  = (const float*)d_in[3];
  const float* b_ih0  = (const float*)d_in[4];
  const float* b_hh0  = (const float*)d_in[5];
  const float* w_ih1  = (const float*)d_in[6];
  const float* w_hh1  = (const float*)d_in[7];
  const float* b_ih1  = (const float*)d_in[8];
  const float* b_hh1  = (const float*)d_in[9];
  const float* w_b0   = (const float*)d_in[10];
  const float* bb_b0  = (const float*)d_in[11];
  const float* w_g    = (const float*)d_in[12];
  const float* b_g    = (const float*)d_in[13];

  float* partials = (float*)d_ws;

  lstm_crps_kernel<<<dim3(NBLK), dim3(NTHR), 0, stream>>>(
      train, labels, w_ih0, w_hh0, b_ih0, b_hh0, w_ih1, w_hh1, b_ih1, b_hh1,
      w_b0, bb_b0, w_g, b_g, partials);
  final_reduce_kernel<<<dim3(1), dim3(NBLK), 0, stream>>>(partials,
                                                          (float*)d_out);
}

// Round 3
// 3373.352 us; speedup vs baseline: 2.1393x; 2.1393x over previous
//
#include <hip/hip_runtime.h>
#include <math.h>

namespace {

constexpr int TT  = 192;   // timesteps
constexpr int INp = 24;    // input features
constexpr int Hh  = 64;    // hidden
constexpr int Kk  = 20;    // spline knots
constexpr int BB  = 8;     // batch rows per block
constexpr int NBLK = 2048 / BB;  // 256 blocks
constexpr int NTHR = 1024;       // 16 waves, 4/SIMD

// big_l columns: [0,24) x | [24,88) h0 | [88,96) zero pad | [96,160) h1 | [160,164) pad
constexpr int CH0 = 24;
constexpr int CH1 = 96;
constexpr int CW  = 164;

__device__ __forceinline__ float sigmoidf_(float x) {
  return 1.0f / (1.0f + __expf(-x));
}
__device__ __forceinline__ float tanhf_(float x) {
  return 2.0f / (1.0f + __expf(-2.0f * x)) - 1.0f;
}
__device__ __forceinline__ float softplusf_(float x) {
  return fmaxf(x, 0.0f) + log1pf(__expf(-fabsf(x)));
}
// sum across lanes {l, l^1, l^2} quads via DPP (VALU only, no LDS)
__device__ __forceinline__ float quad_sum4(float v) {
  int a = __builtin_amdgcn_mov_dpp(__float_as_int(v), 0xB1, 0xf, 0xf, true); // quad_perm 1,0,3,2
  v += __int_as_float(a);
  a = __builtin_amdgcn_mov_dpp(__float_as_int(v), 0x4E, 0xf, 0xf, true);     // quad_perm 2,3,0,1
  v += __int_as_float(a);
  return v;
}

__global__ __launch_bounds__(NTHR, 4) void lstm_crps_kernel(
    const float* __restrict__ train,   // [2048,192,24]
    const float* __restrict__ labels,  // [2048,192]
    const float* __restrict__ w_ih0,   // [256,24]
    const float* __restrict__ w_hh0,   // [256,64]
    const float* __restrict__ b_ih0,   // [256]
    const float* __restrict__ b_hh0,   // [256]
    const float* __restrict__ w_ih1,   // [256,64]
    const float* __restrict__ w_hh1,   // [256,64]
    const float* __restrict__ b_ih1,   // [256]
    const float* __restrict__ b_hh1,   // [256]
    const float* __restrict__ w_b0,    // [1,128]
    const float* __restrict__ bb_b0,   // [1]
    const float* __restrict__ w_g,     // [20,128]
    const float* __restrict__ b_g,     // [20]
    float* __restrict__ partials)      // [NBLK]
{
  __shared__ __align__(16) float big_l[BB][CW];
  __shared__ __align__(16) float gates4[4][BB][256];  // [wk][row][gate]
  __shared__ __align__(16) float wproj[21][132];
  __shared__ float pbias[21];
  __shared__ float bg_l[BB][22];   // [0]=beta0, [1..20]=gamma
  __shared__ float labels_l[BB][TT];
  __shared__ float red_l[NTHR];

  const int tid  = (int)threadIdx.x;
  const int lane = tid & 63;
  const int w    = tid >> 6;     // wave 0..15
  const int wk   = w & 3;        // cross-wave k-quarter
  const int wg   = w >> 2;       // gate set (64 gates)
  const int sub  = lane & 3;     // in-wave k-sub
  const int gp   = lane >> 2;    // gate group in set
  const int idx  = wk * 4 + sub; // k-slice id 0..15
  const int g0   = wg * 64 + gp * 4;  // first of this thread's 4 gates
  const int r0   = (int)blockIdx.x * BB;

  // ---- per-thread weights (56 floats, static-indexed -> VGPRs) ----
  // L0: virtual K=96 = x(24) | h0(64) | pad(8, weight 0). slice = idx*6 .. +6
  // L1: K=128 = h0 via w_ih1 (idx<8) | h1 via w_hh1. slice = (idx&7)*8 .. +8
  float2 wa[4][3];
  float4 wb[4][2];
  float bs0[4], bs1[4];
#pragma unroll
  for (int gi = 0; gi < 4; ++gi) {
    const int g = g0 + gi;
    if (idx < 4) {  // x region
      const float* p = w_ih0 + (size_t)g * 24 + idx * 6;
      wa[gi][0] = *(const float2*)(p + 0);
      wa[gi][1] = *(const float2*)(p + 2);
      wa[gi][2] = *(const float2*)(p + 4);
    } else {        // h0 region (+ zero tail past k=88)
      const float* p = w_hh0 + (size_t)g * 64 - 24;
#pragma unroll
      for (int kc = 0; kc < 3; ++kc) {
        int k0 = idx * 6 + kc * 2;
        float e0 = (k0 + 0 < 88) ? p[k0 + 0] : 0.0f;
        float e1 = (k0 + 1 < 88) ? p[k0 + 1] : 0.0f;
        wa[gi][kc] = make_float2(e0, e1);
      }
    }
    const float* q = ((idx < 8) ? w_ih1 : w_hh1) + (size_t)g * 64 + (idx & 7) * 8;
    wb[gi][0] = *(const float4*)(q + 0);
    wb[gi][1] = *(const float4*)(q + 4);
    bs0[gi] = (idx == 0) ? (b_ih0[g] + b_hh0[g]) : 0.0f;
    bs1[gi] = (idx == 0) ? (b_ih1[g] + b_hh1[g]) : 0.0f;
  }
  // operand column bases in big_l
  const int cL0 = idx * 6;
  const int cL1 = (idx < 8) ? (CH0 + idx * 8) : (CH1 + (idx - 8) * 8);

  // ---- staging ----
  for (int i = tid; i < 21 * 128; i += NTHR) {
    int o = i >> 7, kk2 = i & 127;
    wproj[o][kk2] = (o == 0) ? w_b0[kk2] : w_g[(size_t)(o - 1) * 128 + kk2];
  }
  if (tid < 21) pbias[tid] = (tid == 0) ? bb_b0[0] : b_g[tid - 1];
  for (int i = tid; i < BB * TT; i += NTHR) {
    int r = i / TT, tt = i % TT;
    labels_l[r][tt] = labels[(size_t)(r0 + r) * TT + tt];
  }
  for (int i = tid; i < BB * CW; i += NTHR) (&big_l[0][0])[i] = 0.0f;

  // cell state: tid<512 hold c0 for (tid>>6, tid&63); tid>=512 hold c1
  float cst = 0.0f;
  const int crow0 = tid >> 6;          // for cell L0 (valid when tid<512)
  const int crow1 = (tid - 512) >> 6;  // for cell L1
  const int cf    = tid & 63;

  // x prefetch
  const int xi_r = tid / INp, xi_k = tid % INp;
  float xr = 0.0f;
  if (tid < BB * INp) xr = train[((size_t)(r0 + xi_r) * TT) * INp + xi_k];

  const float sig = 1.0f / (float)Kk;
  const int lcr = tid & 31;
  float myksi = 0.0f;
  for (int i = 0; i < lcr && i < Kk; ++i) myksi += sig;  // cumsum fidelity

  float cacc = 0.0f;

  __syncthreads();
  if (tid < BB * INp) big_l[xi_r][xi_k] = xr;  // x(0)
  __syncthreads();

  for (int t = 0; t < TT; ++t) {
    // ======== Phase G0: layer0 gates ========
    if (tid < BB * INp && (t + 1) < TT)
      xr = train[((size_t)(r0 + xi_r) * TT + (t + 1)) * INp + xi_k];

#pragma unroll
    for (int rc = 0; rc < 2; ++rc) {
      float acc[4][4];
#pragma unroll
      for (int gi = 0; gi < 4; ++gi)
#pragma unroll
        for (int rr = 0; rr < 4; ++rr) acc[gi][rr] = bs0[gi];
#pragma unroll
      for (int kc = 0; kc < 3; ++kc) {
#pragma unroll
        for (int rr = 0; rr < 4; ++rr) {
          float2 v = *(const float2*)&big_l[rc * 4 + rr][cL0 + kc * 2];
#pragma unroll
          for (int gi = 0; gi < 4; ++gi)
            acc[gi][rr] = fmaf(wa[gi][kc].x, v.x,
                          fmaf(wa[gi][kc].y, v.y, acc[gi][rr]));
        }
      }
      float4 wv;
#pragma unroll
      for (int rr = 0; rr < 4; ++rr) {
#pragma unroll
        for (int gi = 0; gi < 4; ++gi) {
          float red = quad_sum4(acc[gi][rr]);
          if (sub == rr) (&wv.x)[gi] = red;
        }
      }
      *(float4*)&gates4[wk][rc * 4 + sub][g0] = wv;
    }
    __syncthreads();  // B2

    // ======== cell L0 (tid<512) ========
    if (tid < 512) {
      float gi_ = gates4[0][crow0][cf] + gates4[1][crow0][cf] +
                  gates4[2][crow0][cf] + gates4[3][crow0][cf];
      float gf_ = gates4[0][crow0][64 + cf] + gates4[1][crow0][64 + cf] +
                  gates4[2][crow0][64 + cf] + gates4[3][crow0][64 + cf];
      float gg_ = gates4[0][crow0][128 + cf] + gates4[1][crow0][128 + cf] +
                  gates4[2][crow0][128 + cf] + gates4[3][crow0][128 + cf];
      float go_ = gates4[0][crow0][192 + cf] + gates4[1][crow0][192 + cf] +
                  gates4[2][crow0][192 + cf] + gates4[3][crow0][192 + cf];
      float c2 = sigmoidf_(gf_) * cst + sigmoidf_(gi_) * tanhf_(gg_);
      cst = c2;
      big_l[crow0][CH0 + cf] = sigmoidf_(go_) * tanhf_(c2);
    }
    __syncthreads();  // B3

    // ======== Phase G1: layer1 gates ========
#pragma unroll
    for (int rc = 0; rc < 2; ++rc) {
      float acc[4][4];
#pragma unroll
      for (int gi = 0; gi < 4; ++gi)
#pragma unroll
        for (int rr = 0; rr < 4; ++rr) acc[gi][rr] = bs1[gi];
#pragma unroll
      for (int kc = 0; kc < 2; ++kc) {
#pragma unroll
        for (int rr = 0; rr < 4; ++rr) {
          float4 v = *(const float4*)&big_l[rc * 4 + rr][cL1 + kc * 4];
#pragma unroll
          for (int gi = 0; gi < 4; ++gi)
            acc[gi][rr] = fmaf(wb[gi][kc].x, v.x,
                          fmaf(wb[gi][kc].y, v.y,
                          fmaf(wb[gi][kc].z, v.z,
                          fmaf(wb[gi][kc].w, v.w, acc[gi][rr]))));
        }
      }
      float4 wv;
#pragma unroll
      for (int rr = 0; rr < 4; ++rr) {
#pragma unroll
        for (int gi = 0; gi < 4; ++gi) {
          float red = quad_sum4(acc[gi][rr]);
          if (sub == rr) (&wv.x)[gi] = red;
        }
      }
      *(float4*)&gates4[wk][rc * 4 + sub][g0] = wv;
    }
    __syncthreads();  // B4

    // ======== cell L1 (tid>=512) + x(t+1) publish (tid<192) ========
    if (tid >= 512) {
      float gi_ = gates4[0][crow1][cf] + gates4[1][crow1][cf] +
                  gates4[2][crow1][cf] + gates4[3][crow1][cf];
      float gf_ = gates4[0][crow1][64 + cf] + gates4[1][crow1][64 + cf] +
                  gates4[2][crow1][64 + cf] + gates4[3][crow1][64 + cf];
      float gg_ = gates4[0][crow1][128 + cf] + gates4[1][crow1][128 + cf] +
                  gates4[2][crow1][128 + cf] + gates4[3][crow1][128 + cf];
      float go_ = gates4[0][crow1][192 + cf] + gates4[1][crow1][192 + cf] +
                  gates4[2][crow1][192 + cf] + gates4[3][crow1][192 + cf];
      float c2 = sigmoidf_(gf_) * cst + sigmoidf_(gi_) * tanhf_(gg_);
      cst = c2;
      big_l[crow1][CH1 + cf] = sigmoidf_(go_) * tanhf_(c2);
    } else if (tid < BB * INp) {
      big_l[xi_r][xi_k] = xr;
    }
    __syncthreads();  // B5

    // ======== projection + softplus (tid<168) ========
    if (tid < BB * 21) {
      int o = tid >> 3, r = tid & 7;
      float lin = pbias[o];
#pragma unroll 16
      for (int h = 0; h < Hh; ++h) {
        float2 wv2 = *(const float2*)&wproj[o][2 * h];
        lin += big_l[r][CH0 + h] * wv2.x + big_l[r][CH1 + h] * wv2.y;
      }
      bg_l[r][o] = softplusf_(lin);
    }
    __syncthreads();  // B6

    // ======== CRPS (tid<256, one 32-lane group per row) ========
    if (tid < 256) {
      const int grp = tid >> 5;
      const int l = tid & 31;
      const bool valid = (l < Kk);
      const float y = labels_l[grp][t];
      const float b0v = bg_l[grp][0];

      float braw = 0.0f;
      if (valid) {
        float gam = bg_l[grp][1 + l];
        float bp  = bg_l[grp][l];
        braw = (gam - bp) / (2.0f * sig);
      }
      float brawm1 = __shfl_up(braw, 1, 32);
      float bj = valid ? (braw - ((l == 0) ? 0.0f : brawm1)) : 0.0f;
      float st = (l < Kk - 1) ? bj : 0.0f;
#pragma unroll
      for (int off = 16; off > 0; off >>= 1) st += __shfl_xor(st, off, 32);
      if (l == Kk - 1) bj = bg_l[grp][Kk] - st;

      float knot = b0v * myksi;
      float kj = 0.0f;
#pragma unroll
      for (int j = 0; j < Kk; ++j) {
        float bjj = __shfl(bj, j, 32);
        float d = fmaxf(myksi - kj, 0.0f);
        knot += bjj * d * d;
        kj += sig;
      }
      float diff = y - knot;
      bool al = valid && (diff > 0.0f);
      float ab = al ? bj : 0.0f;
      float tA = ab;
      float tB = ab * myksi;
      float tC = ab * myksi * myksi;
      float u = 1.0f - myksi;
      float c3t = valid ? (bj * (1.0f / 6.0f)) * (u * u * u * u) : 0.0f;
      float ad = valid ? fabsf(diff) : 3.4e38f;
      int ai = l;
#pragma unroll
      for (int off = 16; off > 0; off >>= 1) {
        tA += __shfl_xor(tA, off, 32);
        tB += __shfl_xor(tB, off, 32);
        tC += __shfl_xor(tC, off, 32);
        c3t += __shfl_xor(c3t, off, 32);
        float oad = __shfl_xor(ad, off, 32);
        int   oai = __shfl_xor(ai, off, 32);
        if (oad < ad || (oad == ad && oai < ai)) { ad = oad; ai = oai; }
      }
      float A   = tA;
      float Bco = b0v - 2.0f * tB;
      float Cc  = -y + tC;
      float disc = Bco * Bco - 4.0f * A * Cc;
      float ksi_pick = __shfl(myksi, ai, 32);
      float A_safe = (A != 0.0f) ? A : 1.0f;
      float B_safe = (Bco != 0.0f) ? Bco : 1.0f;
      float quad = (-Bco + sqrtf(fmaxf(disc, 0.0f))) / (2.0f * A_safe);
      float alpha = (A != 0.0f && disc >= 0.0f)
                        ? quad
                        : ((A == 0.0f) ? (-Cc / B_safe) : ksi_pick);
      float dk = alpha - myksi;
      float c4t = al ? ((2.0f / 3.0f) * bj) * (dk * dk * dk) : 0.0f;
#pragma unroll
      for (int off = 16; off > 0; off >>= 1) c4t += __shfl_xor(c4t, off, 32);
      float crps = y * (2.0f * alpha - 1.0f) +
                   b0v * ((1.0f / 3.0f) - alpha * alpha) + c3t - c4t;
      if (l == 0) cacc += crps;
    }
    // no loop-back barrier: G0(t+1) writes gates4 (last read pre-B5) and
    // reads x/h0 (B5-separated); CRPS reads bg_l/labels_l only.
  }

  // ---- block reduction ----
  red_l[tid] = cacc;
  __syncthreads();
#pragma unroll
  for (int s = NTHR / 2; s > 0; s >>= 1) {
    if (tid < s) red_l[tid] += red_l[tid + s];
    __syncthreads();
  }
  if (tid == 0) partials[blockIdx.x] = red_l[0];
}

__global__ void final_reduce_kernel(const float* __restrict__ partials,
                                    float* __restrict__ out) {
  __shared__ float s_l[NBLK];
  const int tid = (int)threadIdx.x;
  s_l[tid] = partials[tid];
  __syncthreads();
  for (int s = NBLK / 2; s > 0; s >>= 1) {
    if (tid < s) s_l[tid] += s_l[tid + s];
    __syncthreads();
  }
  if (tid == 0) out[0] = s_l[0] * (1.0f / 2048.0f);
}

}  // namespace

extern "C" void kernel_launch(void* const* d_in, const int* in_sizes, int n_in,
                              void* d_out, int out_size, void* d_ws, size_t ws_size,
                              hipStream_t stream) {
  (void)in_sizes; (void)n_in; (void)out_size; (void)ws_size;
  const float* train  = (const float*)d_in[0];
  const float* labels = (const float*)d_in[1];
  const float* w_ih0  = (const float*)d_in[2];
  const float* w_hh0  = (const float*)d_in[3];
  const float* b_ih0  = (const float*)d_in[4];
  const float* b_hh0  = (const float*)d_in[5];
  const float* w_ih1  = (const float*)d_in[6];
  const float* w_hh1  = (const float*)d_in[7];
  const float* b_ih1  = (const float*)d_in[8];
  const float* b_hh1  = (const float*)d_in[9];
  const float* w_b0   = (const float*)d_in[10];
  const float* bb_b0  = (const float*)d_in[11];
  const float* w_g    = (const float*)d_in[12];
  const float* b_g    = (const float*)d_in[13];

  float* partials = (float*)d_ws;

  lstm_crps_kernel<<<dim3(NBLK), dim3(NTHR), 0, stream>>>(
      train, labels, w_ih0, w_hh0, b_ih0, b_hh0, w_ih1, w_hh1, b_ih1, b_hh1,
      w_b0, bb_b0, w_g, b_g, partials);
  final_reduce_kernel<<<dim3(1), dim3(NBLK), 0, stream>>>(partials,
                                                          (float*)d_out);
}

// Round 4
// 2736.869 us; speedup vs baseline: 2.6368x; 1.2326x over previous
//
#include <hip/hip_runtime.h>
#include <math.h>

namespace {

constexpr int TT  = 192;   // timesteps
constexpr int INp = 24;    // input features
constexpr int Hh  = 64;    // hidden
constexpr int Kk  = 20;    // spline knots
constexpr int BB  = 4;     // batch rows per block
constexpr int NBLK = 2048 / BB;  // 512 blocks -> 2 per CU
constexpr int NTHR = 512;        // 8 waves

// big_l columns: [0,24) x | [24,88) h0 | [88,96) zero pad | [96,160) h1 | pad
constexpr int CH0 = 24;
constexpr int CH1 = 96;
constexpr int CW  = 164;

__device__ __forceinline__ float sigmoidf_(float x) {
  return 1.0f / (1.0f + __expf(-x));
}
__device__ __forceinline__ float tanhf_(float x) {
  return 2.0f / (1.0f + __expf(-2.0f * x)) - 1.0f;
}
__device__ __forceinline__ float softplusf_(float x) {
  return fmaxf(x, 0.0f) + log1pf(__expf(-fabsf(x)));
}
// sum across the 4-lane quad {l^1, l^2} via DPP (VALU only)
__device__ __forceinline__ float quad_sum4(float v) {
  int a = __builtin_amdgcn_mov_dpp(__float_as_int(v), 0xB1, 0xf, 0xf, true);
  v += __int_as_float(a);
  a = __builtin_amdgcn_mov_dpp(__float_as_int(v), 0x4E, 0xf, 0xf, true);
  v += __int_as_float(a);
  return v;
}

__global__ __launch_bounds__(NTHR, 2) void lstm_crps_kernel(
    const float* __restrict__ train,   // [2048,192,24]
    const float* __restrict__ labels,  // [2048,192]
    const float* __restrict__ w_ih0,   // [256,24]
    const float* __restrict__ w_hh0,   // [256,64]
    const float* __restrict__ b_ih0,   // [256]
    const float* __restrict__ b_hh0,   // [256]
    const float* __restrict__ w_ih1,   // [256,64]
    const float* __restrict__ w_hh1,   // [256,64]
    const float* __restrict__ b_ih1,   // [256]
    const float* __restrict__ b_hh1,   // [256]
    const float* __restrict__ w_b0,    // [1,128]
    const float* __restrict__ bb_b0,   // [1]
    const float* __restrict__ w_g,     // [20,128]
    const float* __restrict__ b_g,     // [20]
    float* __restrict__ partials)      // [NBLK]
{
  __shared__ __align__(16) float big_l[BB][CW];
  __shared__ __align__(16) float gates2[2][BB][256];  // XOR-swizzled cols
  __shared__ __align__(16) float wproj[21][132];
  __shared__ float pbias[21];
  __shared__ float bias_l[2][256];     // b_ih + b_hh per layer
  __shared__ float bg_l[BB][22];       // [0]=beta0, [1..20]=gamma
  __shared__ float labels_l[BB][TT];
  __shared__ float red_l[NTHR];

  const int tid  = (int)threadIdx.x;
  const int lane = tid & 63;
  const int w    = tid >> 6;      // wave 0..7
  const int wk   = w & 1;         // cross-wave k-half
  const int wg   = w >> 1;        // gate set (64 gates)
  const int sub  = lane & 3;      // in-wave k-sub
  const int gp   = lane >> 2;     // gate group in set
  const int idx  = wk * 4 + sub;  // k-slice 0..7
  const int g0   = wg * 64 + gp * 4;
  const int r0   = (int)blockIdx.x * BB;

  // L0 slice: virtual K=96 = x(24)|h0(64)|pad(8); 12 floats at kb0
  const int kb0 = idx * 12;
  // L1 slice: K=128 = h0 (w_ih1, idx<4) | h1 (w_hh1); 16 floats
  const int kb1 = (idx < 4) ? (CH0 + idx * 16) : (CH1 + (idx - 4) * 16);
  const float* wsel = (idx < 4) ? w_ih1 : w_hh1;
  const int kw1 = (idx & 3) * 16;

  // ---- staging ----
  for (int i = tid; i < 21 * 128; i += NTHR) {
    int o = i >> 7, kk2 = i & 127;
    wproj[o][kk2] = (o == 0) ? w_b0[kk2] : w_g[(size_t)(o - 1) * 128 + kk2];
  }
  if (tid < 21) pbias[tid] = (tid == 0) ? bb_b0[0] : b_g[tid - 1];
  if (tid < 256) bias_l[0][tid] = b_ih0[tid] + b_hh0[tid];
  else           bias_l[1][tid - 256] = b_ih1[tid - 256] + b_hh1[tid - 256];
  for (int i = tid; i < BB * TT; i += NTHR) {
    int r = i / TT, tt = i % TT;
    labels_l[r][tt] = labels[(size_t)(r0 + r) * TT + tt];
  }
  for (int i = tid; i < BB * CW; i += NTHR) (&big_l[0][0])[i] = 0.0f;

  // cell state: tid<256 -> c0 of (tid>>6, tid&63); tid>=256 -> c1
  float cst = 0.0f;
  const int cr0_ = tid >> 6;           // cell L0 row
  const int cr1_ = (tid - 256) >> 6;   // cell L1 row
  const int cf   = tid & 63;

  // x prefetch (rows*INp = 96 threads)
  const int xi_r = tid / INp, xi_k = tid % INp;
  float xr = 0.0f;
  if (tid < BB * INp) xr = train[((size_t)(r0 + xi_r) * TT) * INp + xi_k];

  const float sig = 1.0f / (float)Kk;
  const int lcr = tid & 31;
  float myksi = 0.0f;
  for (int i = 0; i < lcr && i < Kk; ++i) myksi += sig;  // cumsum fidelity

  float cacc = 0.0f;
  int woff = 0;  // opaque 0: defeats LICM on weight loads

  __syncthreads();
  if (tid < BB * INp) big_l[xi_r][xi_k] = xr;  // x(0)
  __syncthreads();

  for (int t = 0; t < TT; ++t) {
    asm volatile("" : "+v"(woff));  // weight addresses become loop-variant

    // ---- issue L0 weight loads (12 x dwordx4) ----
    float4 wa[4][3];
#pragma unroll
    for (int gi = 0; gi < 4; ++gi) {
      const int g = g0 + gi;
#pragma unroll
      for (int c = 0; c < 3; ++c) {
        const int vk = kb0 + c * 4;
        float4 v;
        if (vk < 24)      v = *(const float4*)(w_ih0 + (size_t)g * 24 + vk + woff);
        else if (vk < 88) v = *(const float4*)(w_hh0 + (size_t)g * 64 + (vk - 24) + woff);
        else              v = make_float4(0.f, 0.f, 0.f, 0.f);
        wa[gi][c] = v;
      }
    }
    // ---- issue L1 weight loads, first half (8 x dwordx4) ----
    float4 wb[4][4];
#pragma unroll
    for (int gi = 0; gi < 2; ++gi)
#pragma unroll
      for (int c = 0; c < 4; ++c)
        wb[gi][c] = *(const float4*)(wsel + (size_t)(g0 + gi) * 64 + kw1 + c * 4 + woff);

    // x(t+1) prefetch
    if (tid < BB * INp && (t + 1) < TT)
      xr = train[((size_t)(r0 + xi_r) * TT + (t + 1)) * INp + xi_k];

    // ---- G0: layer0 gate partials ----
    float acc[4][4];  // [gate][row]
#pragma unroll
    for (int gi = 0; gi < 4; ++gi) {
      float bb_ = (idx == 0) ? bias_l[0][g0 + gi] : 0.0f;
#pragma unroll
      for (int r = 0; r < 4; ++r) acc[gi][r] = bb_;
    }
#pragma unroll
    for (int c = 0; c < 3; ++c) {
#pragma unroll
      for (int r = 0; r < 4; ++r) {
        float4 v = *(const float4*)&big_l[r][kb0 + c * 4];
#pragma unroll
        for (int gi = 0; gi < 4; ++gi)
          acc[gi][r] = fmaf(wa[gi][c].x, v.x, fmaf(wa[gi][c].y, v.y,
                       fmaf(wa[gi][c].z, v.z, fmaf(wa[gi][c].w, v.w, acc[gi][r]))));
      }
    }
    {
      float4 wv;
#pragma unroll
      for (int rr = 0; rr < 4; ++rr) {
        float s0_ = quad_sum4(acc[0][rr]);
        float s1_ = quad_sum4(acc[1][rr]);
        float s2_ = quad_sum4(acc[2][rr]);
        float s3_ = quad_sum4(acc[3][rr]);
        if (sub == rr) wv = make_float4(s0_, s1_, s2_, s3_);
      }
      *(float4*)&gates2[wk][sub][g0 ^ (sub * 16)] = wv;  // row-XOR swizzle
    }
    __syncthreads();  // B2

    // ---- issue L1 weight loads, second half ----
#pragma unroll
    for (int gi = 2; gi < 4; ++gi)
#pragma unroll
      for (int c = 0; c < 4; ++c)
        wb[gi][c] = *(const float4*)(wsel + (size_t)(g0 + gi) * 64 + kw1 + c * 4 + woff);

    // ---- cell L0 (tid<256) ----
    if (tid < 256) {
      const int sx = cr0_ * 16;
      const int cfx = cf ^ sx;
      float gi_ = gates2[0][cr0_][cfx]       + gates2[1][cr0_][cfx];
      float gf_ = gates2[0][cr0_][64 + cfx]  + gates2[1][cr0_][64 + cfx];
      float gg_ = gates2[0][cr0_][128 + cfx] + gates2[1][cr0_][128 + cfx];
      float go_ = gates2[0][cr0_][192 + cfx] + gates2[1][cr0_][192 + cfx];
      float c2 = sigmoidf_(gf_) * cst + sigmoidf_(gi_) * tanhf_(gg_);
      cst = c2;
      big_l[cr0_][CH0 + cf] = sigmoidf_(go_) * tanhf_(c2);
    }
    __syncthreads();  // B3

    // ---- G1: layer1 gate partials ----
    float acc1[4][4];
#pragma unroll
    for (int gi = 0; gi < 4; ++gi) {
      float bb_ = (idx == 0) ? bias_l[1][g0 + gi] : 0.0f;
#pragma unroll
      for (int r = 0; r < 4; ++r) acc1[gi][r] = bb_;
    }
#pragma unroll
    for (int c = 0; c < 4; ++c) {
#pragma unroll
      for (int r = 0; r < 4; ++r) {
        float4 v = *(const float4*)&big_l[r][kb1 + c * 4];
#pragma unroll
        for (int gi = 0; gi < 4; ++gi)
          acc1[gi][r] = fmaf(wb[gi][c].x, v.x, fmaf(wb[gi][c].y, v.y,
                        fmaf(wb[gi][c].z, v.z, fmaf(wb[gi][c].w, v.w, acc1[gi][r]))));
      }
    }
    {
      float4 wv;
#pragma unroll
      for (int rr = 0; rr < 4; ++rr) {
        float s0_ = quad_sum4(acc1[0][rr]);
        float s1_ = quad_sum4(acc1[1][rr]);
        float s2_ = quad_sum4(acc1[2][rr]);
        float s3_ = quad_sum4(acc1[3][rr]);
        if (sub == rr) wv = make_float4(s0_, s1_, s2_, s3_);
      }
      *(float4*)&gates2[wk][sub][g0 ^ (sub * 16)] = wv;
    }
    __syncthreads();  // B4

    // ---- cell L1 (tid>=256) + x(t+1) publish (tid<96) ----
    if (tid >= 256) {
      const int sx = cr1_ * 16;
      const int cfx = cf ^ sx;
      float gi_ = gates2[0][cr1_][cfx]       + gates2[1][cr1_][cfx];
      float gf_ = gates2[0][cr1_][64 + cfx]  + gates2[1][cr1_][64 + cfx];
      float gg_ = gates2[0][cr1_][128 + cfx] + gates2[1][cr1_][128 + cfx];
      float go_ = gates2[0][cr1_][192 + cfx] + gates2[1][cr1_][192 + cfx];
      float c2 = sigmoidf_(gf_) * cst + sigmoidf_(gi_) * tanhf_(gg_);
      cst = c2;
      big_l[cr1_][CH1 + cf] = sigmoidf_(go_) * tanhf_(c2);
    } else if (tid < BB * INp) {
      big_l[xi_r][xi_k] = xr;
    }
    __syncthreads();  // B5

    // ---- projection + softplus (tid < 84 = 21 outputs x 4 rows) ----
    if (tid < 21 * BB) {
      int o = tid >> 2, r = tid & 3;
      float lin = pbias[o];
#pragma unroll 16
      for (int h = 0; h < Hh; ++h) {
        float2 wv2 = *(const float2*)&wproj[o][2 * h];
        lin += big_l[r][CH0 + h] * wv2.x + big_l[r][CH1 + h] * wv2.y;
      }
      bg_l[r][o] = softplusf_(lin);
    }
    __syncthreads();  // B6

    // ---- CRPS (tid<128: one 32-lane group per row) ----
    if (tid < 32 * BB) {
      const int grp = tid >> 5;
      const int l = tid & 31;
      const bool valid = (l < Kk);
      const float y = labels_l[grp][t];
      const float b0v = bg_l[grp][0];

      float braw = 0.0f;
      if (valid) {
        float gam = bg_l[grp][1 + l];
        float bp  = bg_l[grp][l];
        braw = (gam - bp) / (2.0f * sig);
      }
      float brawm1 = __shfl_up(braw, 1, 32);
      float bj = valid ? (braw - ((l == 0) ? 0.0f : brawm1)) : 0.0f;
      float st = (l < Kk - 1) ? bj : 0.0f;
#pragma unroll
      for (int off = 16; off > 0; off >>= 1) st += __shfl_xor(st, off, 32);
      if (l == Kk - 1) bj = bg_l[grp][Kk] - st;

      float knot = b0v * myksi;
      float kj = 0.0f;
#pragma unroll
      for (int j = 0; j < Kk; ++j) {
        float bjj = __shfl(bj, j, 32);
        float d = fmaxf(myksi - kj, 0.0f);
        knot += bjj * d * d;
        kj += sig;
      }
      float diff = y - knot;
      bool al = valid && (diff > 0.0f);
      float ab = al ? bj : 0.0f;
      float tA = ab;
      float tB = ab * myksi;
      float tC = ab * myksi * myksi;
      float u = 1.0f - myksi;
      float c3t = valid ? (bj * (1.0f / 6.0f)) * (u * u * u * u) : 0.0f;
      float ad = valid ? fabsf(diff) : 3.4e38f;
      int ai = l;
#pragma unroll
      for (int off = 16; off > 0; off >>= 1) {
        tA += __shfl_xor(tA, off, 32);
        tB += __shfl_xor(tB, off, 32);
        tC += __shfl_xor(tC, off, 32);
        c3t += __shfl_xor(c3t, off, 32);
        float oad = __shfl_xor(ad, off, 32);
        int   oai = __shfl_xor(ai, off, 32);
        if (oad < ad || (oad == ad && oai < ai)) { ad = oad; ai = oai; }
      }
      float A   = tA;
      float Bco = b0v - 2.0f * tB;
      float Cc  = -y + tC;
      float disc = Bco * Bco - 4.0f * A * Cc;
      float ksi_pick = __shfl(myksi, ai, 32);
      float A_safe = (A != 0.0f) ? A : 1.0f;
      float B_safe = (Bco != 0.0f) ? Bco : 1.0f;
      float quad = (-Bco + sqrtf(fmaxf(disc, 0.0f))) / (2.0f * A_safe);
      float alpha = (A != 0.0f && disc >= 0.0f)
                        ? quad
                        : ((A == 0.0f) ? (-Cc / B_safe) : ksi_pick);
      float dk = alpha - myksi;
      float c4t = al ? ((2.0f / 3.0f) * bj) * (dk * dk * dk) : 0.0f;
#pragma unroll
      for (int off = 16; off > 0; off >>= 1) c4t += __shfl_xor(c4t, off, 32);
      float crps = y * (2.0f * alpha - 1.0f) +
                   b0v * ((1.0f / 3.0f) - alpha * alpha) + c3t - c4t;
      if (l == 0) cacc += crps;
    }
    // no loop-back barrier: B5/B6 separate all cross-iteration pairs
  }

  // ---- block reduction ----
  red_l[tid] = cacc;
  __syncthreads();
#pragma unroll
  for (int s = NTHR / 2; s > 0; s >>= 1) {
    if (tid < s) red_l[tid] += red_l[tid + s];
    __syncthreads();
  }
  if (tid == 0) partials[blockIdx.x] = red_l[0];
}

__global__ void final_reduce_kernel(const float* __restrict__ partials,
                                    float* __restrict__ out) {
  __shared__ float s_l[NBLK];
  const int tid = (int)threadIdx.x;
  s_l[tid] = partials[tid];
  __syncthreads();
  for (int s = NBLK / 2; s > 0; s >>= 1) {
    if (tid < s) s_l[tid] += s_l[tid + s];
    __syncthreads();
  }
  if (tid == 0) out[0] = s_l[0] * (1.0f / 2048.0f);
}

}  // namespace

extern "C" void kernel_launch(void* const* d_in, const int* in_sizes, int n_in,
                              void* d_out, int out_size, void* d_ws, size_t ws_size,
                              hipStream_t stream) {
  (void)in_sizes; (void)n_in; (void)out_size; (void)ws_size;
  const float* train  = (const float*)d_in[0];
  const float* labels = (const float*)d_in[1];
  const float* w_ih0  = (const float*)d_in[2];
  const float* w_hh0  = (const float*)d_in[3];
  const float* b_ih0  = (const float*)d_in[4];
  const float* b_hh0  = (const float*)d_in[5];
  const float* w_ih1  = (const float*)d_in[6];
  const float* w_hh1  = (const float*)d_in[7];
  const float* b_ih1  = (const float*)d_in[8];
  const float* b_hh1  = (const float*)d_in[9];
  const float* w_b0   = (const float*)d_in[10];
  const float* bb_b0  = (const float*)d_in[11];
  const float* w_g    = (const float*)d_in[12];
  const float* b_g    = (const float*)d_in[13];

  float* partials = (float*)d_ws;

  lstm_crps_kernel<<<dim3(NBLK), dim3(NTHR), 0, stream>>>(
      train, labels, w_ih0, w_hh0, b_ih0, b_hh0, w_ih1, w_hh1, b_ih1, b_hh1,
      w_b0, bb_b0, w_g, b_g, partials);
  final_reduce_kernel<<<dim3(1), dim3(NBLK), 0, stream>>>(partials,
                                                          (float*)d_out);
}

// Round 5
// 2644.698 us; speedup vs baseline: 2.7287x; 1.0349x over previous
//
#include <hip/hip_runtime.h>
#include <math.h>

namespace {

constexpr int TT  = 192;   // timesteps
constexpr int INp = 24;    // input features
constexpr int Hh  = 64;    // hidden
constexpr int Kk  = 20;    // spline knots
constexpr int BB  = 8;     // batch rows per block
constexpr int NBLK = 2048 / BB;  // 256 blocks, 1 per CU
constexpr int NTHR = 512;        // 8 waves, 2/SIMD

// big_l columns: [0,24) x | [24,88) h0 | [88,96) zero pad | [96,160) h1 | pad
constexpr int CH0 = 24;
constexpr int CH1 = 96;
constexpr int CW  = 164;
constexpr int NGP = 264;   // gates_l padded row stride

__device__ __forceinline__ float sigmoidf_(float x) {
  return 1.0f / (1.0f + __expf(-x));
}
__device__ __forceinline__ float tanhf_(float x) {
  return 2.0f / (1.0f + __expf(-2.0f * x)) - 1.0f;
}
__device__ __forceinline__ float softplusf_(float x) {
  return fmaxf(x, 0.0f) + log1pf(__expf(-fabsf(x)));
}
// butterfly sum over each 4-lane quad via DPP (VALU only); result in all 4 lanes
__device__ __forceinline__ float quad_sum4(float v) {
  int a = __builtin_amdgcn_mov_dpp(__float_as_int(v), 0xB1, 0xf, 0xf, true);
  v += __int_as_float(a);
  a = __builtin_amdgcn_mov_dpp(__float_as_int(v), 0x4E, 0xf, 0xf, true);
  v += __int_as_float(a);
  return v;
}
__device__ __forceinline__ float dot4(float4 a, float4 b, float acc) {
  return fmaf(a.x, b.x, fmaf(a.y, b.y, fmaf(a.z, b.z, fmaf(a.w, b.w, acc))));
}

__global__ __launch_bounds__(NTHR, 2) void lstm_crps_kernel(
    const float* __restrict__ train,   // [2048,192,24]
    const float* __restrict__ labels,  // [2048,192]
    const float* __restrict__ w_ih0,   // [256,24]
    const float* __restrict__ w_hh0,   // [256,64]
    const float* __restrict__ b_ih0,   // [256]
    const float* __restrict__ b_hh0,   // [256]
    const float* __restrict__ w_ih1,   // [256,64]
    const float* __restrict__ w_hh1,   // [256,64]
    const float* __restrict__ b_ih1,   // [256]
    const float* __restrict__ b_hh1,   // [256]
    const float* __restrict__ w_b0,    // [1,128]
    const float* __restrict__ bb_b0,   // [1]
    const float* __restrict__ w_g,     // [20,128]
    const float* __restrict__ b_g,     // [20]
    float* __restrict__ partials)      // [NBLK]
{
  __shared__ __align__(16) float big_l[BB][CW];
  __shared__ __align__(16) float gates_l[BB][NGP];
  __shared__ __align__(16) float wproj[21][132];
  __shared__ float pbias[21];
  __shared__ float bg_l[BB][22];       // [0]=beta0, [1..20]=gamma
  __shared__ float labels_l[BB][TT];
  __shared__ float red_l[NTHR];

  const int tid   = (int)threadIdx.x;
  const int lane  = tid & 63;
  const int w     = tid >> 6;       // wave 0..7
  const int sub   = lane & 3;       // in-wave k-slice 0..3
  const int gpair = lane >> 2;      // 0..15
  const int g0    = (w * 16 + gpair) * 2;  // even gate id; thread owns g0, g0+1
  const int r0    = (int)blockIdx.x * BB;

  // L0 k-slice: virtual K=96 = x(24) | h0(64) | zero pad(8); 24 floats each
  const int kb0 = sub * 24;
  // L1 k-slice: K=128 = h0 (w_ih1, sub<2) | h1 (w_hh1); 32 floats each
  const int ob1 = (sub < 2) ? (CH0 + sub * 32) : (CH1 + (sub - 2) * 32);
  const float* wsel = (sub < 2) ? w_ih1 : w_hh1;
  const int kw1 = (sub & 1) * 32;

  // ---- staging ----
  for (int i = tid; i < 21 * 128; i += NTHR) {
    int o = i >> 7, kk2 = i & 127;
    wproj[o][kk2] = (o == 0) ? w_b0[kk2] : w_g[(size_t)(o - 1) * 128 + kk2];
  }
  if (tid < 21) pbias[tid] = (tid == 0) ? bb_b0[0] : b_g[tid - 1];
  for (int i = tid; i < BB * TT; i += NTHR) {
    int r = i / TT, tt = i % TT;
    labels_l[r][tt] = labels[(size_t)(r0 + r) * TT + tt];
  }
  for (int i = tid; i < BB * CW; i += NTHR) (&big_l[0][0])[i] = 0.0f;

  // cell: thread = (row = w, feat = lane); c0,c1 both in registers
  const int crow = w;
  const int cf   = lane;
  float c0 = 0.0f, c1 = 0.0f;
  const float bi0 = b_ih0[cf]       + b_hh0[cf];
  const float bf0 = b_ih0[64 + cf]  + b_hh0[64 + cf];
  const float bg0 = b_ih0[128 + cf] + b_hh0[128 + cf];
  const float bo0 = b_ih0[192 + cf] + b_hh0[192 + cf];
  const float bi1 = b_ih1[cf]       + b_hh1[cf];
  const float bf1 = b_ih1[64 + cf]  + b_hh1[64 + cf];
  const float bg1 = b_ih1[128 + cf] + b_hh1[128 + cf];
  const float bo1 = b_ih1[192 + cf] + b_hh1[192 + cf];

  // x prefetch (BB*INp = 192 threads)
  const int xi_r = tid / INp, xi_k = tid % INp;
  float xr = 0.0f;
  if (tid < BB * INp) xr = train[((size_t)(r0 + xi_r) * TT) * INp + xi_k];

  const float sig = 1.0f / (float)Kk;
  const int lcr = tid & 31;
  float myksi = 0.0f;
  for (int i = 0; i < lcr && i < Kk; ++i) myksi += sig;  // cumsum fidelity

  float cacc = 0.0f;
  int woff = 0;  // opaque 0: defeats LICM on weight loads (proved in R4)

  __syncthreads();
  if (tid < BB * INp) big_l[xi_r][xi_k] = xr;  // x(0)
  __syncthreads();

  for (int t = 0; t < TT; ++t) {
    asm volatile("" : "+v"(woff));  // weight addresses loop-variant

    // ---- issue L0 weight loads (12 x b128: 2 gates x 6) ----
    float4 wa0[6], wa1[6];
#pragma unroll
    for (int c = 0; c < 6; ++c) {
      const int vk = kb0 + c * 4;
      if (vk < 24) {
        wa0[c] = *(const float4*)(w_ih0 + (size_t)g0 * 24 + vk + woff);
        wa1[c] = *(const float4*)(w_ih0 + (size_t)(g0 + 1) * 24 + vk + woff);
      } else if (vk < 88) {
        wa0[c] = *(const float4*)(w_hh0 + (size_t)g0 * 64 + (vk - 24) + woff);
        wa1[c] = *(const float4*)(w_hh0 + (size_t)(g0 + 1) * 64 + (vk - 24) + woff);
      } else {
        wa0[c] = make_float4(0.f, 0.f, 0.f, 0.f);
        wa1[c] = make_float4(0.f, 0.f, 0.f, 0.f);
      }
    }
    // x(t+1) prefetch
    if (tid < BB * INp && (t + 1) < TT)
      xr = train[((size_t)(r0 + xi_r) * TT + (t + 1)) * INp + xi_k];

    // ---- G0: layer0 gate dot-products over 8 rows ----
    float acc0[BB], acc1[BB];
#pragma unroll
    for (int r = 0; r < BB; ++r) { acc0[r] = 0.0f; acc1[r] = 0.0f; }
#pragma unroll
    for (int c = 0; c < 6; ++c) {
#pragma unroll
      for (int r = 0; r < BB; ++r) {
        float4 v = *(const float4*)&big_l[r][kb0 + c * 4];
        acc0[r] = dot4(wa0[c], v, acc0[r]);
        acc1[r] = dot4(wa1[c], v, acc1[r]);
      }
    }
    // in-wave quad reduce; lane sub stores rows {sub, sub+4}
    {
      float lo0 = 0.f, lo1 = 0.f, hi0 = 0.f, hi1 = 0.f;
#pragma unroll
      for (int r = 0; r < BB; ++r) {
        float s0 = quad_sum4(acc0[r]);
        float s1 = quad_sum4(acc1[r]);
        if (r == sub)     { lo0 = s0; lo1 = s1; }
        if (r == sub + 4) { hi0 = s0; hi1 = s1; }
      }
      *(float2*)&gates_l[sub][g0]     = make_float2(lo0, lo1);
      *(float2*)&gates_l[sub + 4][g0] = make_float2(hi0, hi1);
    }
    __syncthreads();  // B1

    // ---- issue L1 weight loads (16 x b128) under cell0's latency ----
    float4 wb0[8], wb1[8];
#pragma unroll
    for (int c = 0; c < 8; ++c) {
      wb0[c] = *(const float4*)(wsel + (size_t)g0 * 64 + kw1 + c * 4 + woff);
      wb1[c] = *(const float4*)(wsel + (size_t)(g0 + 1) * 64 + kw1 + c * 4 + woff);
    }

    // ---- cell L0 (all 512 threads: 8 rows x 64 feats) ----
    {
      float gi_ = gates_l[crow][cf]       + bi0;
      float gf_ = gates_l[crow][64 + cf]  + bf0;
      float gg_ = gates_l[crow][128 + cf] + bg0;
      float go_ = gates_l[crow][192 + cf] + bo0;
      float c2 = sigmoidf_(gf_) * c0 + sigmoidf_(gi_) * tanhf_(gg_);
      c0 = c2;
      big_l[crow][CH0 + cf] = sigmoidf_(go_) * tanhf_(c2);
    }
    __syncthreads();  // B2

    // ---- G1: layer1 gate dot-products ----
#pragma unroll
    for (int r = 0; r < BB; ++r) { acc0[r] = 0.0f; acc1[r] = 0.0f; }
#pragma unroll
    for (int c = 0; c < 8; ++c) {
#pragma unroll
      for (int r = 0; r < BB; ++r) {
        float4 v = *(const float4*)&big_l[r][ob1 + c * 4];
        acc0[r] = dot4(wb0[c], v, acc0[r]);
        acc1[r] = dot4(wb1[c], v, acc1[r]);
      }
    }
    {
      float lo0 = 0.f, lo1 = 0.f, hi0 = 0.f, hi1 = 0.f;
#pragma unroll
      for (int r = 0; r < BB; ++r) {
        float s0 = quad_sum4(acc0[r]);
        float s1 = quad_sum4(acc1[r]);
        if (r == sub)     { lo0 = s0; lo1 = s1; }
        if (r == sub + 4) { hi0 = s0; hi1 = s1; }
      }
      *(float2*)&gates_l[sub][g0]     = make_float2(lo0, lo1);
      *(float2*)&gates_l[sub + 4][g0] = make_float2(hi0, hi1);
    }
    __syncthreads();  // B3

    // ---- cell L1 (all 512) + x(t+1) publish (tid<192) ----
    {
      float gi_ = gates_l[crow][cf]       + bi1;
      float gf_ = gates_l[crow][64 + cf]  + bf1;
      float gg_ = gates_l[crow][128 + cf] + bg1;
      float go_ = gates_l[crow][192 + cf] + bo1;
      float c2 = sigmoidf_(gf_) * c1 + sigmoidf_(gi_) * tanhf_(gg_);
      c1 = c2;
      big_l[crow][CH1 + cf] = sigmoidf_(go_) * tanhf_(c2);
    }
    if (tid < BB * INp) big_l[xi_r][xi_k] = xr;
    __syncthreads();  // B4

    // ---- projection + softplus, 2-way h-split (tid < 336 = 21*8*2) ----
    if (tid < 21 * BB * 2) {
      const int u = tid >> 1, half = tid & 1;
      const int o = u >> 3, r = u & 7;
      float lin = (half == 0) ? pbias[o] : 0.0f;
      const int hbeg = half * 32;
#pragma unroll 16
      for (int h = hbeg; h < hbeg + 32; ++h) {
        float2 wv2 = *(const float2*)&wproj[o][2 * h];
        lin += big_l[r][CH0 + h] * wv2.x + big_l[r][CH1 + h] * wv2.y;
      }
      float other = __shfl_xor(lin, 1, 64);
      if (half == 0) bg_l[r][o] = softplusf_(lin + other);
    }
    __syncthreads();  // B5

    // ---- CRPS (tid<256: one 32-lane group per row) ----
    if (tid < 32 * BB) {
      const int grp = tid >> 5;
      const int l = tid & 31;
      const bool valid = (l < Kk);
      const float y = labels_l[grp][t];
      const float b0v = bg_l[grp][0];

      float braw = 0.0f;
      if (valid) {
        float gam = bg_l[grp][1 + l];
        float bp  = bg_l[grp][l];
        braw = (gam - bp) / (2.0f * sig);
      }
      float brawm1 = __shfl_up(braw, 1, 32);
      float bj = valid ? (braw - ((l == 0) ? 0.0f : brawm1)) : 0.0f;
      float st = (l < Kk - 1) ? bj : 0.0f;
#pragma unroll
      for (int off = 16; off > 0; off >>= 1) st += __shfl_xor(st, off, 32);
      if (l == Kk - 1) bj = bg_l[grp][Kk] - st;

      float knot = b0v * myksi;
      float kj = 0.0f;
#pragma unroll
      for (int j = 0; j < Kk; ++j) {
        float bjj = __shfl(bj, j, 32);
        float d = fmaxf(myksi - kj, 0.0f);
        knot += bjj * d * d;
        kj += sig;
      }
      float diff = y - knot;
      bool al = valid && (diff > 0.0f);
      float ab = al ? bj : 0.0f;
      float tA = ab;
      float tB = ab * myksi;
      float tC = ab * myksi * myksi;
      float u4 = 1.0f - myksi;
      float c3t = valid ? (bj * (1.0f / 6.0f)) * (u4 * u4 * u4 * u4) : 0.0f;
      float ad = valid ? fabsf(diff) : 3.4e38f;
      int ai = l;
#pragma unroll
      for (int off = 16; off > 0; off >>= 1) {
        tA += __shfl_xor(tA, off, 32);
        tB += __shfl_xor(tB, off, 32);
        tC += __shfl_xor(tC, off, 32);
        c3t += __shfl_xor(c3t, off, 32);
        float oad = __shfl_xor(ad, off, 32);
        int   oai = __shfl_xor(ai, off, 32);
        if (oad < ad || (oad == ad && oai < ai)) { ad = oad; ai = oai; }
      }
      float A   = tA;
      float Bco = b0v - 2.0f * tB;
      float Cc  = -y + tC;
      float disc = Bco * Bco - 4.0f * A * Cc;
      float ksi_pick = __shfl(myksi, ai, 32);
      float A_safe = (A != 0.0f) ? A : 1.0f;
      float B_safe = (Bco != 0.0f) ? Bco : 1.0f;
      float quad = (-Bco + sqrtf(fmaxf(disc, 0.0f))) / (2.0f * A_safe);
      float alpha = (A != 0.0f && disc >= 0.0f)
                        ? quad
                        : ((A == 0.0f) ? (-Cc / B_safe) : ksi_pick);
      float dk = alpha - myksi;
      float c4t = al ? ((2.0f / 3.0f) * bj) * (dk * dk * dk) : 0.0f;
#pragma unroll
      for (int off = 16; off > 0; off >>= 1) c4t += __shfl_xor(c4t, off, 32);
      float crps = y * (2.0f * alpha - 1.0f) +
                   b0v * ((1.0f / 3.0f) - alpha * alpha) + c3t - c4t;
      if (l == 0) cacc += crps;
    }
    // no loop-back barrier: G0(t+1) writes gates_l (readers cell0/cell1 are
    // B1/B3-separated next iter; proj/CRPS never touch gates_l); h0/h1/x
    // writes all happen after the barriers that close their readers.
  }

  // ---- block reduction ----
  red_l[tid] = cacc;
  __syncthreads();
#pragma unroll
  for (int s = NTHR / 2; s > 0; s >>= 1) {
    if (tid < s) red_l[tid] += red_l[tid + s];
    __syncthreads();
  }
  if (tid == 0) partials[blockIdx.x] = red_l[0];
}

__global__ void final_reduce_kernel(const float* __restrict__ partials,
                                    float* __restrict__ out) {
  __shared__ float s_l[NBLK];
  const int tid = (int)threadIdx.x;
  s_l[tid] = partials[tid];
  __syncthreads();
  for (int s = NBLK / 2; s > 0; s >>= 1) {
    if (tid < s) s_l[tid] += s_l[tid + s];
    __syncthreads();
  }
  if (tid == 0) out[0] = s_l[0] * (1.0f / 2048.0f);
}

}  // namespace

extern "C" void kernel_launch(void* const* d_in, const int* in_sizes, int n_in,
                              void* d_out, int out_size, void* d_ws, size_t ws_size,
                              hipStream_t stream) {
  (void)in_sizes; (void)n_in; (void)out_size; (void)ws_size;
  const float* train  = (const float*)d_in[0];
  const float* labels = (const float*)d_in[1];
  const float* w_ih0  = (const float*)d_in[2];
  const float* w_hh0  = (const float*)d_in[3];
  const float* b_ih0  = (const float*)d_in[4];
  const float* b_hh0  = (const float*)d_in[5];
  const float* w_ih1  = (const float*)d_in[6];
  const float* w_hh1  = (const float*)d_in[7];
  const float* b_ih1  = (const float*)d_in[8];
  const float* b_hh1  = (const float*)d_in[9];
  const float* w_b0   = (const float*)d_in[10];
  const float* bb_b0  = (const float*)d_in[11];
  const float* w_g    = (const float*)d_in[12];
  const float* b_g    = (const float*)d_in[13];

  float* partials = (float*)d_ws;

  lstm_crps_kernel<<<dim3(NBLK), dim3(NTHR), 0, stream>>>(
      train, labels, w_ih0, w_hh0, b_ih0, b_hh0, w_ih1, w_hh1, b_ih1, b_hh1,
      w_b0, bb_b0, w_g, b_g, partials);
  final_reduce_kernel<<<dim3(1), dim3(NBLK), 0, stream>>>(partials,
                                                          (float*)d_out);
}

// Round 6
// 2346.571 us; speedup vs baseline: 3.0754x; 1.1270x over previous
//
#include <hip/hip_runtime.h>
#include <math.h>

namespace {

constexpr int TT  = 192;   // timesteps
constexpr int INp = 24;    // input features
constexpr int Hh  = 64;    // hidden
constexpr int Kk  = 20;    // spline knots
constexpr int BB  = 8;     // batch rows per block (= waves)
constexpr int NBLK = 2048 / BB;  // 256 blocks, 1 per CU
constexpr int NTHR = 512;        // 8 waves, 2/SIMD

// big_l columns: [0,24) x | [24,88) h0 | [88,96) zero pad | [96,160) h1 | pad
constexpr int CH0 = 24;
constexpr int CH1 = 96;
constexpr int CW  = 164;
constexpr int NGP = 264;   // gates_l padded row stride

__device__ __forceinline__ float sigmoidf_(float x) {
  return 1.0f / (1.0f + __expf(-x));
}
__device__ __forceinline__ float tanhf_(float x) {
  return 2.0f / (1.0f + __expf(-2.0f * x)) - 1.0f;
}
__device__ __forceinline__ float softplusf_(float x) {
  return fmaxf(x, 0.0f) + log1pf(__expf(-fabsf(x)));
}
// butterfly sum over 4-lane quad via DPP (VALU only)
__device__ __forceinline__ float quad_sum4(float v) {
  int a = __builtin_amdgcn_mov_dpp(__float_as_int(v), 0xB1, 0xf, 0xf, true);
  v += __int_as_float(a);
  a = __builtin_amdgcn_mov_dpp(__float_as_int(v), 0x4E, 0xf, 0xf, true);
  v += __int_as_float(a);
  return v;
}
// butterfly sum over 8-lane group: quad sum + row_half_mirror (lane ^7 == ^4
// after quads are equalized)
__device__ __forceinline__ float oct_sum8(float v) {
  v = quad_sum4(v);
  int a = __builtin_amdgcn_mov_dpp(__float_as_int(v), 0x141, 0xf, 0xf, true);
  return v + __int_as_float(a);
}
__device__ __forceinline__ float dot4(float4 a, float4 b, float acc) {
  return fmaf(a.x, b.x, fmaf(a.y, b.y, fmaf(a.z, b.z, fmaf(a.w, b.w, acc))));
}

#define WAVE_LDS_FENCE()                                  \
  do {                                                    \
    asm volatile("s_waitcnt lgkmcnt(0)" ::: "memory");    \
    __builtin_amdgcn_sched_barrier(0);                    \
  } while (0)

__global__ __launch_bounds__(NTHR, 2) void lstm_crps_kernel(
    const float* __restrict__ train,   // [2048,192,24]
    const float* __restrict__ labels,  // [2048,192]
    const float* __restrict__ w_ih0,   // [256,24]
    const float* __restrict__ w_hh0,   // [256,64]
    const float* __restrict__ b_ih0,   // [256]
    const float* __restrict__ b_hh0,   // [256]
    const float* __restrict__ w_ih1,   // [256,64]
    const float* __restrict__ w_hh1,   // [256,64]
    const float* __restrict__ b_ih1,   // [256]
    const float* __restrict__ b_hh1,   // [256]
    const float* __restrict__ w_b0,    // [1,128]
    const float* __restrict__ bb_b0,   // [1]
    const float* __restrict__ w_g,     // [20,128]
    const float* __restrict__ b_g,     // [20]
    float* __restrict__ partials)      // [NBLK]
{
  __shared__ __align__(16) float big_l[BB][CW];
  __shared__ __align__(16) float gates_l[BB][NGP];
  __shared__ __align__(16) float wproj[21][132];
  __shared__ float pbias[21];
  __shared__ float wscr[BB][24];       // per-row beta0/gamma scratch
  __shared__ float labels_l[BB][TT];
  __shared__ float red_l[NTHR];

  const int tid  = (int)threadIdx.x;
  const int lane = tid & 63;
  const int w    = tid >> 6;      // wave == batch row for cell/proj/CRPS
  const int sub3 = lane & 7;      // k-slice 0..7
  const int gq   = lane >> 3;     // gate-quad 0..7
  const int g0   = w * 32 + gq * 4;  // first of this thread's 4 gates
  const int r0   = (int)blockIdx.x * BB;

  // L0: virtual K=96 = x(24) | h0(64) | zero pad(8); slice = 12 floats
  const int kb0 = sub3 * 12;
  // L1: K=128 = h0 (w_ih1, sub3<4) | h1 (w_hh1); slice = 16 floats
  const int ob1 = (sub3 < 4) ? (CH0 + sub3 * 16) : (CH1 + (sub3 - 4) * 16);
  const float* wsel = (sub3 < 4) ? w_ih1 : w_hh1;
  const int kw1 = (sub3 & 3) * 16;

  // ---- staging ----
  for (int i = tid; i < 21 * 128; i += NTHR) {
    int o = i >> 7, kk2 = i & 127;
    wproj[o][kk2] = (o == 0) ? w_b0[kk2] : w_g[(size_t)(o - 1) * 128 + kk2];
  }
  if (tid < 21) pbias[tid] = (tid == 0) ? bb_b0[0] : b_g[tid - 1];
  for (int i = tid; i < BB * TT; i += NTHR) {
    int r = i / TT, tt = i % TT;
    labels_l[r][tt] = labels[(size_t)(r0 + r) * TT + tt];
  }
  for (int i = tid; i < BB * CW; i += NTHR) (&big_l[0][0])[i] = 0.0f;

  // cell biases for unit `lane` (same across waves)
  const float bi0 = b_ih0[lane]       + b_hh0[lane];
  const float bf0 = b_ih0[64 + lane]  + b_hh0[64 + lane];
  const float bg0 = b_ih0[128 + lane] + b_hh0[128 + lane];
  const float bo0 = b_ih0[192 + lane] + b_hh0[192 + lane];
  const float bi1 = b_ih1[lane]       + b_hh1[lane];
  const float bf1 = b_ih1[64 + lane]  + b_hh1[64 + lane];
  const float bg1 = b_ih1[128 + lane] + b_hh1[128 + lane];
  const float bo1 = b_ih1[192 + lane] + b_hh1[192 + lane];
  float c0 = 0.0f, c1 = 0.0f;

  // x prefetch (BB*INp = 192 threads)
  const int xi_r = tid / INp, xi_k = tid % INp;
  float xr = 0.0f;
  if (tid < BB * INp) xr = train[((size_t)(r0 + xi_r) * TT) * INp + xi_k];

  const float sig = 1.0f / (float)Kk;
  const int lcr = tid & 31;
  float myksi = 0.0f;
  for (int i = 0; i < lcr && i < Kk; ++i) myksi += sig;  // cumsum fidelity

  float cacc = 0.0f;
  int woff = 0;  // opaque 0: keeps per-iteration weight loads loop-variant

  // ---- prologue weight loads (t=0) ----
  float4 wa[4][3];   // L0: 4 gates x 12 floats
  float4 wb[4][4];   // L1: 4 gates x 16 floats
#pragma unroll
  for (int gi = 0; gi < 4; ++gi) {
    const int g = g0 + gi;
#pragma unroll
    for (int c = 0; c < 3; ++c) {
      const int vk = kb0 + c * 4;
      if (vk < 24)      wa[gi][c] = *(const float4*)(w_ih0 + (size_t)g * 24 + vk);
      else if (vk < 88) wa[gi][c] = *(const float4*)(w_hh0 + (size_t)g * 64 + (vk - 24));
      else              wa[gi][c] = make_float4(0.f, 0.f, 0.f, 0.f);
    }
#pragma unroll
    for (int c = 0; c < 4; ++c)
      wb[gi][c] = *(const float4*)(wsel + (size_t)g * 64 + kw1 + c * 4);
  }

  __syncthreads();
  if (tid < BB * INp) big_l[xi_r][xi_k] = xr;  // x(0)
  __syncthreads();

  for (int t = 0; t < TT; ++t) {
    asm volatile("" : "+v"(woff));  // defeat LICM on weight reloads

    // x(t+1) prefetch
    if (tid < BB * INp && (t + 1) < TT)
      xr = train[((size_t)(r0 + xi_r) * TT + (t + 1)) * INp + xi_k];

    // ======== G0: layer0 gates (uses wa prefetched last iter) ========
    float acc[4][BB];
#pragma unroll
    for (int gi = 0; gi < 4; ++gi)
#pragma unroll
      for (int r = 0; r < BB; ++r) acc[gi][r] = 0.0f;
#pragma unroll
    for (int c = 0; c < 3; ++c) {
#pragma unroll
      for (int r = 0; r < BB; ++r) {
        float4 v = *(const float4*)&big_l[r][kb0 + c * 4];
#pragma unroll
        for (int gi = 0; gi < 4; ++gi) acc[gi][r] = dot4(wa[gi][c], v, acc[gi][r]);
      }
    }
    {
      float4 wv;
#pragma unroll
      for (int r = 0; r < BB; ++r) {
        float s0 = oct_sum8(acc[0][r]);
        float s1 = oct_sum8(acc[1][r]);
        float s2 = oct_sum8(acc[2][r]);
        float s3 = oct_sum8(acc[3][r]);
        if (r == sub3) wv = make_float4(s0, s1, s2, s3);
      }
      *(float4*)&gates_l[sub3][g0] = wv;
    }
    __syncthreads();  // B1

    // ======== cell0 phase: issue wa(t+1), then wave-local cell ========
#pragma unroll
    for (int gi = 0; gi < 4; ++gi) {
      const int g = g0 + gi;
#pragma unroll
      for (int c = 0; c < 3; ++c) {
        const int vk = kb0 + c * 4;
        if (vk < 24)      wa[gi][c] = *(const float4*)(w_ih0 + (size_t)g * 24 + vk + woff);
        else if (vk < 88) wa[gi][c] = *(const float4*)(w_hh0 + (size_t)g * 64 + (vk - 24) + woff);
        else              wa[gi][c] = make_float4(0.f, 0.f, 0.f, 0.f);
      }
    }
    {
      float gi_ = gates_l[w][lane]       + bi0;
      float gf_ = gates_l[w][64 + lane]  + bf0;
      float gg_ = gates_l[w][128 + lane] + bg0;
      float go_ = gates_l[w][192 + lane] + bo0;
      float cn = sigmoidf_(gf_) * c0 + sigmoidf_(gi_) * tanhf_(gg_);
      c0 = cn;
      big_l[w][CH0 + lane] = sigmoidf_(go_) * tanhf_(cn);
    }
    __syncthreads();  // B2

    // ======== G1: layer1 gates (uses wb prefetched last iter) ========
#pragma unroll
    for (int gi = 0; gi < 4; ++gi)
#pragma unroll
      for (int r = 0; r < BB; ++r) acc[gi][r] = 0.0f;
#pragma unroll
    for (int c = 0; c < 4; ++c) {
#pragma unroll
      for (int r = 0; r < BB; ++r) {
        float4 v = *(const float4*)&big_l[r][ob1 + c * 4];
#pragma unroll
        for (int gi = 0; gi < 4; ++gi) acc[gi][r] = dot4(wb[gi][c], v, acc[gi][r]);
      }
    }
    {
      float4 wv;
#pragma unroll
      for (int r = 0; r < BB; ++r) {
        float s0 = oct_sum8(acc[0][r]);
        float s1 = oct_sum8(acc[1][r]);
        float s2 = oct_sum8(acc[2][r]);
        float s3 = oct_sum8(acc[3][r]);
        if (r == sub3) wv = make_float4(s0, s1, s2, s3);
      }
      *(float4*)&gates_l[sub3][g0] = wv;
    }
    __syncthreads();  // B3

    // ======== fat phase (wave-local): wb(t+1) issue, cell1, x publish,
    //          projection, CRPS — no block barriers inside ========
#pragma unroll
    for (int gi = 0; gi < 4; ++gi)
#pragma unroll
      for (int c = 0; c < 4; ++c)
        wb[gi][c] = *(const float4*)(wsel + (size_t)(g0 + gi) * 64 + kw1 + c * 4 + woff);

    {
      float gi_ = gates_l[w][lane]       + bi1;
      float gf_ = gates_l[w][64 + lane]  + bf1;
      float gg_ = gates_l[w][128 + lane] + bg1;
      float go_ = gates_l[w][192 + lane] + bo1;
      float cn = sigmoidf_(gf_) * c1 + sigmoidf_(gi_) * tanhf_(gg_);
      c1 = cn;
      big_l[w][CH1 + lane] = sigmoidf_(go_) * tanhf_(cn);
    }
    if (tid < BB * INp) big_l[xi_r][xi_k] = xr;

    WAVE_LDS_FENCE();  // h1 writes visible to this wave's cross-lane reads

    // ---- projection + softplus: lanes 0..41 = (o, h-half) pairs ----
    if (lane < 42) {
      const int o = lane >> 1, half = lane & 1;
      float lin = (half == 0) ? pbias[o] : 0.0f;
      const int hbeg = half * 32;
#pragma unroll 16
      for (int h = hbeg; h < hbeg + 32; ++h) {
        float2 wv2 = *(const float2*)&wproj[o][2 * h];
        lin += big_l[w][CH0 + h] * wv2.x + big_l[w][CH1 + h] * wv2.y;
      }
      lin += __shfl_xor(lin, 1, 64);
      if (half == 0) wscr[w][o] = softplusf_(lin);
    }

    WAVE_LDS_FENCE();  // wscr visible

    // ---- CRPS (all lanes; both 32-halves duplicate, lane 0 accumulates) ----
    {
      const int l = lcr;               // 0..31
      const bool valid = (l < Kk);
      const float y = labels_l[w][t];
      const float b0v = wscr[w][0];

      float braw = 0.0f;
      if (valid) {
        float gam = wscr[w][1 + l];
        float bp  = wscr[w][l];
        braw = (gam - bp) / (2.0f * sig);
      }
      float brawm1 = __shfl_up(braw, 1, 32);
      float bj = valid ? (braw - ((l == 0) ? 0.0f : brawm1)) : 0.0f;
      float st = (l < Kk - 1) ? bj : 0.0f;
#pragma unroll
      for (int off = 16; off > 0; off >>= 1) st += __shfl_xor(st, off, 32);
      if (l == Kk - 1) bj = wscr[w][Kk] - st;

      float knot = b0v * myksi;
      float kj = 0.0f;
#pragma unroll
      for (int j = 0; j < Kk; ++j) {
        float bjj = __shfl(bj, j, 32);
        float d = fmaxf(myksi - kj, 0.0f);
        knot += bjj * d * d;
        kj += sig;
      }
      float diff = y - knot;
      bool al = valid && (diff > 0.0f);
      float ab = al ? bj : 0.0f;
      float tA = ab;
      float tB = ab * myksi;
      float tC = ab * myksi * myksi;
      float u4 = 1.0f - myksi;
      float c3t = valid ? (bj * (1.0f / 6.0f)) * (u4 * u4 * u4 * u4) : 0.0f;
      float ad = valid ? fabsf(diff) : 3.4e38f;
      int ai = l;
#pragma unroll
      for (int off = 16; off > 0; off >>= 1) {
        tA += __shfl_xor(tA, off, 32);
        tB += __shfl_xor(tB, off, 32);
        tC += __shfl_xor(tC, off, 32);
        c3t += __shfl_xor(c3t, off, 32);
        float oad = __shfl_xor(ad, off, 32);
        int   oai = __shfl_xor(ai, off, 32);
        if (oad < ad || (oad == ad && oai < ai)) { ad = oad; ai = oai; }
      }
      float A   = tA;
      float Bco = b0v - 2.0f * tB;
      float Cc  = -y + tC;
      float disc = Bco * Bco - 4.0f * A * Cc;
      float ksi_pick = __shfl(myksi, ai, 32);
      float A_safe = (A != 0.0f) ? A : 1.0f;
      float B_safe = (Bco != 0.0f) ? Bco : 1.0f;
      float quad = (-Bco + sqrtf(fmaxf(disc, 0.0f))) / (2.0f * A_safe);
      float alpha = (A != 0.0f && disc >= 0.0f)
                        ? quad
                        : ((A == 0.0f) ? (-Cc / B_safe) : ksi_pick);
      float dk = alpha - myksi;
      float c4t = al ? ((2.0f / 3.0f) * bj) * (dk * dk * dk) : 0.0f;
#pragma unroll
      for (int off = 16; off > 0; off >>= 1) c4t += __shfl_xor(c4t, off, 32);
      float crps = y * (2.0f * alpha - 1.0f) +
                   b0v * ((1.0f / 3.0f) - alpha * alpha) + c3t - c4t;
      if (lane == 0) cacc += crps;
    }
    __syncthreads();  // B4: h1/x published for next G0/G1; gates_l free
  }

  // ---- block reduction ----
  red_l[tid] = cacc;
  __syncthreads();
#pragma unroll
  for (int s = NTHR / 2; s > 0; s >>= 1) {
    if (tid < s) red_l[tid] += red_l[tid + s];
    __syncthreads();
  }
  if (tid == 0) partials[blockIdx.x] = red_l[0];
}

__global__ void final_reduce_kernel(const float* __restrict__ partials,
                                    float* __restrict__ out) {
  __shared__ float s_l[NBLK];
  const int tid = (int)threadIdx.x;
  s_l[tid] = partials[tid];
  __syncthreads();
  for (int s = NBLK / 2; s > 0; s >>= 1) {
    if (tid < s) s_l[tid] += s_l[tid + s];
    __syncthreads();
  }
  if (tid == 0) out[0] = s_l[0] * (1.0f / 2048.0f);
}

}  // namespace

extern "C" void kernel_launch(void* const* d_in, const int* in_sizes, int n_in,
                              void* d_out, int out_size, void* d_ws, size_t ws_size,
                              hipStream_t stream) {
  (void)in_sizes; (void)n_in; (void)out_size; (void)ws_size;
  const float* train  = (const float*)d_in[0];
  const float* labels = (const float*)d_in[1];
  const float* w_ih0  = (const float*)d_in[2];
  const float* w_hh0  = (const float*)d_in[3];
  const float* b_ih0  = (const float*)d_in[4];
  const float* b_hh0  = (const float*)d_in[5];
  const float* w_ih1  = (const float*)d_in[6];
  const float* w_hh1  = (const float*)d_in[7];
  const float* b_ih1  = (const float*)d_in[8];
  const float* b_hh1  = (const float*)d_in[9];
  const float* w_b0   = (const float*)d_in[10];
  const float* bb_b0  = (const float*)d_in[11];
  const float* w_g    = (const float*)d_in[12];
  const float* b_g    = (const float*)d_in[13];

  float* partials = (float*)d_ws;

  lstm_crps_kernel<<<dim3(NBLK), dim3(NTHR), 0, stream>>>(
      train, labels, w_ih0, w_hh0, b_ih0, b_hh0, w_ih1, w_hh1, b_ih1, b_hh1,
      w_b0, bb_b0, w_g, b_g, partials);
  final_reduce_kernel<<<dim3(1), dim3(NBLK), 0, stream>>>(partials,
                                                          (float*)d_out);
}

// Round 7
// 1277.974 us; speedup vs baseline: 5.6469x; 1.8362x over previous
//
#include <hip/hip_runtime.h>
#include <math.h>

namespace {

constexpr int TT  = 192;
constexpr int INp = 24;
constexpr int Hh  = 64;
constexpr int Kk  = 20;
constexpr int BB  = 8;            // batch rows per block (= waves)
constexpr int NBLK = 2048 / BB;   // 256 blocks
constexpr int NTHR = 512;         // 8 waves

// packed-weight workspace layout (uints): wsA[256][48] | wsB[256][64] | partials
constexpr int WSA_U = 256 * 48;   // 12288
constexpr int WSB_U = 256 * 64;   // 16384
constexpr int NWU   = WSA_U + WSB_U;  // 28672 uints = 114688 B

__device__ __forceinline__ float sigmoidf_(float x) {
  return 1.0f / (1.0f + __expf(-x));
}
__device__ __forceinline__ float tanhf_(float x) {
  return 2.0f / (1.0f + __expf(-2.0f * x)) - 1.0f;
}
__device__ __forceinline__ float softplusf_(float x) {
  return fmaxf(x, 0.0f) + log1pf(__expf(-fabsf(x)));
}
__device__ __forceinline__ float quad_sum4(float v) {
  int a = __builtin_amdgcn_mov_dpp(__float_as_int(v), 0xB1, 0xf, 0xf, true);
  v += __int_as_float(a);
  a = __builtin_amdgcn_mov_dpp(__float_as_int(v), 0x4E, 0xf, 0xf, true);
  v += __int_as_float(a);
  return v;
}
// acc += dot2(bf16x2 w, bf16x2 v) on the bf16 dot pipe
#define DOT2(acc, wv, vv) \
  asm("v_dot2_f32_bf16 %0, %1, %2, %0" : "+v"(acc) : "v"(wv), "v"(vv))
// pack two fp32 -> bf16x2 (lo = a, hi = b)
__device__ __forceinline__ unsigned cvt_pk_bf16(float a, float b) {
  unsigned r;
  asm("v_cvt_pk_bf16_f32 %0, %1, %2" : "=v"(r) : "v"(a), "v"(b));
  return r;
}

#define WAVE_LDS_FENCE()                                  \
  do {                                                    \
    asm volatile("s_waitcnt lgkmcnt(0)" ::: "memory");    \
    __builtin_amdgcn_sched_barrier(0);                    \
  } while (0)

__device__ __forceinline__ unsigned bf16rne(float x) {
  unsigned u = __float_as_uint(x);
  return (u + 0x7FFFu + ((u >> 16) & 1u)) >> 16;
}

// ---- convert weights to packed bf16 in ws (runs every launch; deterministic)
__global__ void wconv_kernel(const float* __restrict__ w_ih0,
                             const float* __restrict__ w_hh0,
                             const float* __restrict__ w_ih1,
                             const float* __restrict__ w_hh1,
                             unsigned* __restrict__ out) {
  int i = (int)(blockIdx.x * 256 + threadIdx.x);
  if (i >= NWU) return;
  float lo = 0.f, hi = 0.f;
  if (i < WSA_U) {
    int g = i / 48, j = i % 48;   // L0 virtual K=96: x(24)|h0(64)|pad(8)
    if (j < 12)      { lo = w_ih0[g * 24 + 2 * j]; hi = w_ih0[g * 24 + 2 * j + 1]; }
    else if (j < 44) { lo = w_hh0[g * 64 + 2 * (j - 12)]; hi = w_hh0[g * 64 + 2 * (j - 12) + 1]; }
  } else {
    int i2 = i - WSA_U;
    int g = i2 / 64, j = i2 % 64; // L1 K=128: h0(w_ih1)|h1(w_hh1)
    if (j < 32) { lo = w_ih1[g * 64 + 2 * j]; hi = w_ih1[g * 64 + 2 * j + 1]; }
    else        { lo = w_hh1[g * 64 + 2 * (j - 32)]; hi = w_hh1[g * 64 + 2 * (j - 32) + 1]; }
  }
  out[i] = bf16rne(lo) | (bf16rne(hi) << 16);
}

__global__ __launch_bounds__(NTHR, 2) void lstm_crps_kernel(
    const float* __restrict__ train,   // [2048,192,24]
    const float* __restrict__ labels,  // [2048,192]
    const float* __restrict__ b_ih0, const float* __restrict__ b_hh0,
    const float* __restrict__ b_ih1, const float* __restrict__ b_hh1,
    const float* __restrict__ w_b0, const float* __restrict__ bb_b0,
    const float* __restrict__ w_g,  const float* __restrict__ b_g,
    const unsigned* __restrict__ wsA,  // [256][48] packed bf16
    const unsigned* __restrict__ wsB,  // [256][64] packed bf16
    float* __restrict__ partials)      // [NBLK]
{
  __shared__ __align__(16) unsigned xpk_l[BB][TT * 12];  // x packed bf16
  __shared__ __align__(16) unsigned hpk_l[BB][64];       // h0(32)|h1(32) packed
  __shared__ __align__(16) float bigh_l[BB][132];        // fp32 h0|h1 for proj
  __shared__ __align__(16) float gates_l[BB][264];
  __shared__ __align__(16) float wproj[21][132];
  __shared__ float pbias[21];
  __shared__ float wscr[BB][24];
  __shared__ float labels_l[BB][TT];
  __shared__ float red_l[NTHR];

  const int tid   = (int)threadIdx.x;
  const int lane  = tid & 63;
  const int w     = tid >> 6;       // wave == batch row
  const int sub   = lane & 3;       // k-slice 0..3
  const int gpair = lane >> 2;      // 0..15
  const int g0    = w * 32 + gpair * 2;  // thread owns gates g0, g0+1
  const int r0    = (int)blockIdx.x * BB;

  // ---- staging ----
  for (int i = tid; i < 21 * 128; i += NTHR) {
    int o = i >> 7, kk2 = i & 127;
    wproj[o][kk2] = (o == 0) ? w_b0[kk2] : w_g[(size_t)(o - 1) * 128 + kk2];
  }
  if (tid < 21) pbias[tid] = (tid == 0) ? bb_b0[0] : b_g[tid - 1];
  for (int i = tid; i < BB * TT; i += NTHR) {
    int r = i / TT, tt = i % TT;
    labels_l[r][tt] = labels[(size_t)(r0 + r) * TT + tt];
  }
  for (int i = tid; i < BB * 64; i += NTHR) (&hpk_l[0][0])[i] = 0u;  // finite t=0
  // pack the whole x sequence once: 8 rows x 192 t x 12 uints
  for (int i = tid; i < BB * TT * 12; i += NTHR) {
    int r = i / (TT * 12), rem = i % (TT * 12);
    int t = rem / 12, u = rem % 12;
    const float* p = train + ((size_t)(r0 + r) * TT + t) * INp + 2 * u;
    float2 v = *(const float2*)p;
    xpk_l[r][t * 12 + u] = cvt_pk_bf16(v.x, v.y);
  }

  // ---- persistent packed weights (56 uints -> VGPRs) ----
  uint4 wa[2][3], wb[2][4];
#pragma unroll
  for (int gi = 0; gi < 2; ++gi) {
    const unsigned* pa = wsA + (size_t)(g0 + gi) * 48 + sub * 12;
    wa[gi][0] = *(const uint4*)(pa + 0);
    wa[gi][1] = *(const uint4*)(pa + 4);
    wa[gi][2] = *(const uint4*)(pa + 8);
    const unsigned* pb = wsB + (size_t)(g0 + gi) * 64 + sub * 16;
    wb[gi][0] = *(const uint4*)(pb + 0);
    wb[gi][1] = *(const uint4*)(pb + 4);
    wb[gi][2] = *(const uint4*)(pb + 8);
    wb[gi][3] = *(const uint4*)(pb + 12);
  }

  // cell biases for unit `lane`
  const float bi0 = b_ih0[lane]       + b_hh0[lane];
  const float bf0 = b_ih0[64 + lane]  + b_hh0[64 + lane];
  const float bg0 = b_ih0[128 + lane] + b_hh0[128 + lane];
  const float bo0 = b_ih0[192 + lane] + b_hh0[192 + lane];
  const float bi1 = b_ih1[lane]       + b_hh1[lane];
  const float bf1 = b_ih1[64 + lane]  + b_hh1[64 + lane];
  const float bg1 = b_ih1[128 + lane] + b_hh1[128 + lane];
  const float bo1 = b_ih1[192 + lane] + b_hh1[192 + lane];
  float c0 = 0.0f, c1 = 0.0f;

  const float sig = 1.0f / (float)Kk;
  const int lcr = tid & 31;
  float myksi = 0.0f;
  for (int i = 0; i < lcr && i < Kk; ++i) myksi += sig;  // cumsum fidelity

  float cacc = 0.0f;
  const int hoff0 = (sub == 0) ? 0 : (sub - 1) * 12;  // L0 h0-region slice

  __syncthreads();

  for (int t = 0; t < TT; ++t) {
    // ======== G0: layer0 gates ========
    float a0[BB], a1[BB];
#pragma unroll
    for (int r = 0; r < BB; ++r) { a0[r] = 0.0f; a1[r] = 0.0f; }
    {
      const unsigned* base = (sub == 0) ? &xpk_l[0][t * 12] : &hpk_l[0][hoff0];
      const int ostr = (sub == 0) ? (TT * 12) : 64;
#pragma unroll
      for (int r = 0; r < BB; ++r) {
        const unsigned* p = base + r * ostr;
        uint4 va = *(const uint4*)(p);
        uint4 vb = *(const uint4*)(p + 4);
        uint4 vc = *(const uint4*)(p + 8);
        DOT2(a0[r], wa[0][0].x, va.x); DOT2(a1[r], wa[1][0].x, va.x);
        DOT2(a0[r], wa[0][0].y, va.y); DOT2(a1[r], wa[1][0].y, va.y);
        DOT2(a0[r], wa[0][0].z, va.z); DOT2(a1[r], wa[1][0].z, va.z);
        DOT2(a0[r], wa[0][0].w, va.w); DOT2(a1[r], wa[1][0].w, va.w);
        DOT2(a0[r], wa[0][1].x, vb.x); DOT2(a1[r], wa[1][1].x, vb.x);
        DOT2(a0[r], wa[0][1].y, vb.y); DOT2(a1[r], wa[1][1].y, vb.y);
        DOT2(a0[r], wa[0][1].z, vb.z); DOT2(a1[r], wa[1][1].z, vb.z);
        DOT2(a0[r], wa[0][1].w, vb.w); DOT2(a1[r], wa[1][1].w, vb.w);
        DOT2(a0[r], wa[0][2].x, vc.x); DOT2(a1[r], wa[1][2].x, vc.x);
        DOT2(a0[r], wa[0][2].y, vc.y); DOT2(a1[r], wa[1][2].y, vc.y);
        DOT2(a0[r], wa[0][2].z, vc.z); DOT2(a1[r], wa[1][2].z, vc.z);
        DOT2(a0[r], wa[0][2].w, vc.w); DOT2(a1[r], wa[1][2].w, vc.w);
      }
    }
    {
      float2 wlo, whi;
#pragma unroll
      for (int r = 0; r < BB; ++r) {
        float s0 = quad_sum4(a0[r]);
        float s1 = quad_sum4(a1[r]);
        if (r == sub)     wlo = make_float2(s0, s1);
        if (r == sub + 4) whi = make_float2(s0, s1);
      }
      *(float2*)&gates_l[sub][g0]     = wlo;
      *(float2*)&gates_l[sub + 4][g0] = whi;
    }
    __syncthreads();  // B1

    // ======== cell L0 (all 512) + pack h0 ========
    {
      float gi_ = gates_l[w][lane]       + bi0;
      float gf_ = gates_l[w][64 + lane]  + bf0;
      float gg_ = gates_l[w][128 + lane] + bg0;
      float go_ = gates_l[w][192 + lane] + bo0;
      float cn = sigmoidf_(gf_) * c0 + sigmoidf_(gi_) * tanhf_(gg_);
      c0 = cn;
      float h = sigmoidf_(go_) * tanhf_(cn);
      bigh_l[w][lane] = h;
      float nb = __shfl_xor(h, 1, 64);
      unsigned pk = cvt_pk_bf16(h, nb);
      if ((lane & 1) == 0) hpk_l[w][lane >> 1] = pk;
    }
    __syncthreads();  // B2

    // ======== G1: layer1 gates ========
#pragma unroll
    for (int r = 0; r < BB; ++r) { a0[r] = 0.0f; a1[r] = 0.0f; }
    {
      const unsigned* base = &hpk_l[0][sub * 16];
#pragma unroll
      for (int r = 0; r < BB; ++r) {
        const unsigned* p = base + r * 64;
        uint4 va = *(const uint4*)(p);
        uint4 vb = *(const uint4*)(p + 4);
        uint4 vc = *(const uint4*)(p + 8);
        uint4 vd = *(const uint4*)(p + 12);
        DOT2(a0[r], wb[0][0].x, va.x); DOT2(a1[r], wb[1][0].x, va.x);
        DOT2(a0[r], wb[0][0].y, va.y); DOT2(a1[r], wb[1][0].y, va.y);
        DOT2(a0[r], wb[0][0].z, va.z); DOT2(a1[r], wb[1][0].z, va.z);
        DOT2(a0[r], wb[0][0].w, va.w); DOT2(a1[r], wb[1][0].w, va.w);
        DOT2(a0[r], wb[0][1].x, vb.x); DOT2(a1[r], wb[1][1].x, vb.x);
        DOT2(a0[r], wb[0][1].y, vb.y); DOT2(a1[r], wb[1][1].y, vb.y);
        DOT2(a0[r], wb[0][1].z, vb.z); DOT2(a1[r], wb[1][1].z, vb.z);
        DOT2(a0[r], wb[0][1].w, vb.w); DOT2(a1[r], wb[1][1].w, vb.w);
        DOT2(a0[r], wb[0][2].x, vc.x); DOT2(a1[r], wb[1][2].x, vc.x);
        DOT2(a0[r], wb[0][2].y, vc.y); DOT2(a1[r], wb[1][2].y, vc.y);
        DOT2(a0[r], wb[0][2].z, vc.z); DOT2(a1[r], wb[1][2].z, vc.z);
        DOT2(a0[r], wb[0][2].w, vc.w); DOT2(a1[r], wb[1][2].w, vc.w);
        DOT2(a0[r], wb[0][3].x, vd.x); DOT2(a1[r], wb[1][3].x, vd.x);
        DOT2(a0[r], wb[0][3].y, vd.y); DOT2(a1[r], wb[1][3].y, vd.y);
        DOT2(a0[r], wb[0][3].z, vd.z); DOT2(a1[r], wb[1][3].z, vd.z);
        DOT2(a0[r], wb[0][3].w, vd.w); DOT2(a1[r], wb[1][3].w, vd.w);
      }
    }
    {
      float2 wlo, whi;
#pragma unroll
      for (int r = 0; r < BB; ++r) {
        float s0 = quad_sum4(a0[r]);
        float s1 = quad_sum4(a1[r]);
        if (r == sub)     wlo = make_float2(s0, s1);
        if (r == sub + 4) whi = make_float2(s0, s1);
      }
      *(float2*)&gates_l[sub][g0]     = wlo;
      *(float2*)&gates_l[sub + 4][g0] = whi;
    }
    __syncthreads();  // B3

    // ======== fat phase (wave-local): cell1, proj, CRPS ========
    {
      float gi_ = gates_l[w][lane]       + bi1;
      float gf_ = gates_l[w][64 + lane]  + bf1;
      float gg_ = gates_l[w][128 + lane] + bg1;
      float go_ = gates_l[w][192 + lane] + bo1;
      float cn = sigmoidf_(gf_) * c1 + sigmoidf_(gi_) * tanhf_(gg_);
      c1 = cn;
      float h = sigmoidf_(go_) * tanhf_(cn);
      bigh_l[w][64 + lane] = h;
      float nb = __shfl_xor(h, 1, 64);
      unsigned pk = cvt_pk_bf16(h, nb);
      if ((lane & 1) == 0) hpk_l[w][32 + (lane >> 1)] = pk;
    }

    WAVE_LDS_FENCE();  // h0/h1 fp32+packed visible within wave

    // ---- projection + softplus: lanes 0..41 = (o, h-half) ----
    if (lane < 42) {
      const int o = lane >> 1, half = lane & 1;
      float lin = (half == 0) ? pbias[o] : 0.0f;
      const int hbeg = half * 32;
#pragma unroll 16
      for (int h = hbeg; h < hbeg + 32; ++h) {
        float2 wv2 = *(const float2*)&wproj[o][2 * h];
        lin += bigh_l[w][h] * wv2.x + bigh_l[w][64 + h] * wv2.y;
      }
      lin += __shfl_xor(lin, 1, 64);
      if (half == 0) wscr[w][o] = softplusf_(lin);
    }

    WAVE_LDS_FENCE();  // wscr visible

    // ---- CRPS (all lanes; 32-halves duplicate; lane 0 accumulates) ----
    {
      const int l = lcr;
      const bool valid = (l < Kk);
      const float y = labels_l[w][t];
      const float b0v = wscr[w][0];

      float braw = 0.0f;
      if (valid) {
        float gam = wscr[w][1 + l];
        float bp  = wscr[w][l];
        braw = (gam - bp) / (2.0f * sig);
      }
      float brawm1 = __shfl_up(braw, 1, 32);
      float bj = valid ? (braw - ((l == 0) ? 0.0f : brawm1)) : 0.0f;
      float st = (l < Kk - 1) ? bj : 0.0f;
#pragma unroll
      for (int off = 16; off > 0; off >>= 1) st += __shfl_xor(st, off, 32);
      if (l == Kk - 1) bj = wscr[w][Kk] - st;

      float knot = b0v * myksi;
      float kj = 0.0f;
#pragma unroll
      for (int j = 0; j < Kk; ++j) {
        float bjj = __shfl(bj, j, 32);
        float d = fmaxf(myksi - kj, 0.0f);
        knot += bjj * d * d;
        kj += sig;
      }
      float diff = y - knot;
      bool al = valid && (diff > 0.0f);
      float ab = al ? bj : 0.0f;
      float tA = ab;
      float tB = ab * myksi;
      float tC = ab * myksi * myksi;
      float u4 = 1.0f - myksi;
      float c3t = valid ? (bj * (1.0f / 6.0f)) * (u4 * u4 * u4 * u4) : 0.0f;
      float ad = valid ? fabsf(diff) : 3.4e38f;
      int ai = l;
#pragma unroll
      for (int off = 16; off > 0; off >>= 1) {
        tA += __shfl_xor(tA, off, 32);
        tB += __shfl_xor(tB, off, 32);
        tC += __shfl_xor(tC, off, 32);
        c3t += __shfl_xor(c3t, off, 32);
        float oad = __shfl_xor(ad, off, 32);
        int   oai = __shfl_xor(ai, off, 32);
        if (oad < ad || (oad == ad && oai < ai)) { ad = oad; ai = oai; }
      }
      float A   = tA;
      float Bco = b0v - 2.0f * tB;
      float Cc  = -y + tC;
      float disc = Bco * Bco - 4.0f * A * Cc;
      float ksi_pick = __shfl(myksi, ai, 32);
      float A_safe = (A != 0.0f) ? A : 1.0f;
      float B_safe = (Bco != 0.0f) ? Bco : 1.0f;
      float quad = (-Bco + sqrtf(fmaxf(disc, 0.0f))) / (2.0f * A_safe);
      float alpha = (A != 0.0f && disc >= 0.0f)
                        ? quad
                        : ((A == 0.0f) ? (-Cc / B_safe) : ksi_pick);
      float dk = alpha - myksi;
      float c4t = al ? ((2.0f / 3.0f) * bj) * (dk * dk * dk) : 0.0f;
#pragma unroll
      for (int off = 16; off > 0; off >>= 1) c4t += __shfl_xor(c4t, off, 32);
      float crps = y * (2.0f * alpha - 1.0f) +
                   b0v * ((1.0f / 3.0f) - alpha * alpha) + c3t - c4t;
      if (lane == 0) cacc += crps;
    }
    __syncthreads();  // B4
  }

  // ---- block reduction ----
  red_l[tid] = cacc;
  __syncthreads();
#pragma unroll
  for (int s = NTHR / 2; s > 0; s >>= 1) {
    if (tid < s) red_l[tid] += red_l[tid + s];
    __syncthreads();
  }
  if (tid == 0) partials[blockIdx.x] = red_l[0];
}

__global__ void final_reduce_kernel(const float* __restrict__ partials,
                                    float* __restrict__ out) {
  __shared__ float s_l[NBLK];
  const int tid = (int)threadIdx.x;
  s_l[tid] = partials[tid];
  __syncthreads();
  for (int s = NBLK / 2; s > 0; s >>= 1) {
    if (tid < s) s_l[tid] += s_l[tid + s];
    __syncthreads();
  }
  if (tid == 0) out[0] = s_l[0] * (1.0f / 2048.0f);
}

}  // namespace

extern "C" void kernel_launch(void* const* d_in, const int* in_sizes, int n_in,
                              void* d_out, int out_size, void* d_ws, size_t ws_size,
                              hipStream_t stream) {
  (void)in_sizes; (void)n_in; (void)out_size; (void)ws_size;
  const float* train  = (const float*)d_in[0];
  const float* labels = (const float*)d_in[1];
  const float* w_ih0  = (const float*)d_in[2];
  const float* w_hh0  = (const float*)d_in[3];
  const float* b_ih0  = (const float*)d_in[4];
  const float* b_hh0  = (const float*)d_in[5];
  const float* w_ih1  = (const float*)d_in[6];
  const float* w_hh1  = (const float*)d_in[7];
  const float* b_ih1  = (const float*)d_in[8];
  const float* b_hh1  = (const float*)d_in[9];
  const float* w_b0   = (const float*)d_in[10];
  const float* bb_b0  = (const float*)d_in[11];
  const float* w_g    = (const float*)d_in[12];
  const float* b_g    = (const float*)d_in[13];

  unsigned* wsA = (unsigned*)d_ws;
  unsigned* wsB = wsA + WSA_U;
  float* partials = (float*)((char*)d_ws + (size_t)NWU * 4);

  wconv_kernel<<<dim3((NWU + 255) / 256), dim3(256), 0, stream>>>(
      w_ih0, w_hh0, w_ih1, w_hh1, wsA);
  lstm_crps_kernel<<<dim3(NBLK), dim3(NTHR), 0, stream>>>(
      train, labels, b_ih0, b_hh0, b_ih1, b_hh1,
      w_b0, bb_b0, w_g, b_g, wsA, wsB, partials);
  final_reduce_kernel<<<dim3(1), dim3(NBLK), 0, stream>>>(partials,
                                                          (float*)d_out);
}

// Round 8
// 824.042 us; speedup vs baseline: 8.7576x; 1.5509x over previous
//
#include <hip/hip_runtime.h>
#include <math.h>

namespace {

constexpr int TT  = 192;
constexpr int INp = 24;
constexpr int Hh  = 64;
constexpr int Kk  = 20;
constexpr int BB  = 8;            // batch rows per block (= waves)
constexpr int NBLK = 2048 / BB;   // 256 blocks
constexpr int NTHR = 512;         // 8 waves

// packed-weight workspace (uints): wsA[256][48] | wsB[256][64] | partials
constexpr int WSA_U = 256 * 48;
constexpr int WSB_U = 256 * 64;
constexpr int NWU   = WSA_U + WSB_U;

// LDS strides (uints/floats) padded so row-stride % 32 != 0 (bank spread)
constexpr int XSTR = 2308;   // xpk row: 192*12 = 2304 used
constexpr int HSTR = 68;     // hpk row: h0[0..32) | h1[32..64)
constexpr int GSTR = 268;    // gates row

using short8 = __attribute__((ext_vector_type(8))) short;  // 8 bf16
using f32x4  = __attribute__((ext_vector_type(4))) float;

__device__ __forceinline__ float sigmoidf_(float x) {
  return 1.0f / (1.0f + __expf(-x));
}
__device__ __forceinline__ float tanhf_(float x) {
  return 2.0f / (1.0f + __expf(-2.0f * x)) - 1.0f;
}
__device__ __forceinline__ float softplusf_(float x) {
  return fmaxf(x, 0.0f) + log1pf(__expf(-fabsf(x)));
}
__device__ __forceinline__ unsigned cvt_pk_bf16(float a, float b) {
  unsigned r;
  asm("v_cvt_pk_bf16_f32 %0, %1, %2" : "=v"(r) : "v"(a), "v"(b));
  return r;
}
__device__ __forceinline__ unsigned bf16rne(float x) {
  unsigned u = __float_as_uint(x);
  return (u + 0x7FFFu + ((u >> 16) & 1u)) >> 16;
}
__device__ __forceinline__ short8 as_bf(uint4 u) {
  short8 s; __builtin_memcpy(&s, &u, 16); return s;
}

#define WAVE_LDS_FENCE()                                  \
  do {                                                    \
    asm volatile("s_waitcnt lgkmcnt(0)" ::: "memory");    \
    __builtin_amdgcn_sched_barrier(0);                    \
  } while (0)

// ---- convert weights to packed bf16 (k-pair contiguous) ----
__global__ void wconv_kernel(const float* __restrict__ w_ih0,
                             const float* __restrict__ w_hh0,
                             const float* __restrict__ w_ih1,
                             const float* __restrict__ w_hh1,
                             unsigned* __restrict__ out) {
  int i = (int)(blockIdx.x * 256 + threadIdx.x);
  if (i >= NWU) return;
  float lo = 0.f, hi = 0.f;
  if (i < WSA_U) {
    int g = i / 48, j = i % 48;   // L0 virtual K=96: x(24)|h0(64)|pad(8)
    if (j < 12)      { lo = w_ih0[g * 24 + 2 * j]; hi = w_ih0[g * 24 + 2 * j + 1]; }
    else if (j < 44) { lo = w_hh0[g * 64 + 2 * (j - 12)]; hi = w_hh0[g * 64 + 2 * (j - 12) + 1]; }
  } else {
    int i2 = i - WSA_U;
    int g = i2 / 64, j = i2 % 64; // L1 K=128: h0(w_ih1)|h1(w_hh1)
    if (j < 32) { lo = w_ih1[g * 64 + 2 * j]; hi = w_ih1[g * 64 + 2 * j + 1]; }
    else        { lo = w_hh1[g * 64 + 2 * (j - 32)]; hi = w_hh1[g * 64 + 2 * (j - 32) + 1]; }
  }
  out[i] = bf16rne(lo) | (bf16rne(hi) << 16);
}

__global__ __launch_bounds__(NTHR, 1) void lstm_crps_kernel(
    const float* __restrict__ train,   // [2048,192,24]
    const float* __restrict__ labels,  // [2048,192]
    const float* __restrict__ b_ih0, const float* __restrict__ b_hh0,
    const float* __restrict__ b_ih1, const float* __restrict__ b_hh1,
    const float* __restrict__ w_b0, const float* __restrict__ bb_b0,
    const float* __restrict__ w_g,  const float* __restrict__ b_g,
    const unsigned* __restrict__ wsA,  // [256][48] packed bf16
    const unsigned* __restrict__ wsB,  // [256][64] packed bf16
    float* __restrict__ partials)      // [NBLK]
{
  __shared__ __align__(16) unsigned xpk_l[BB][XSTR];
  __shared__ __align__(16) unsigned hpk_l[BB][HSTR];
  __shared__ __align__(16) float bigh_l[BB][132];
  __shared__ __align__(16) float gates_l[BB][GSTR];
  __shared__ __align__(16) float wproj[21][132];
  __shared__ float pbias[21];
  __shared__ float wscr[BB][24];
  __shared__ float labels_l[BB][TT];
  __shared__ float red_l[NTHR];

  const int tid   = (int)threadIdx.x;
  const int lane  = tid & 63;
  const int w     = tid >> 6;       // wave == batch row owner
  const int l15   = lane & 15;
  const int grp   = lane >> 4;      // k-group 0..3
  const int row_a = lane & 7;       // A-operand source row (rows 8-15 dup)
  const int r0    = (int)blockIdx.x * BB;

  // ---- staging ----
  for (int i = tid; i < 21 * 128; i += NTHR) {
    int o = i >> 7, kk2 = i & 127;
    wproj[o][kk2] = (o == 0) ? w_b0[kk2] : w_g[(size_t)(o - 1) * 128 + kk2];
  }
  if (tid < 21) pbias[tid] = (tid == 0) ? bb_b0[0] : b_g[tid - 1];
  for (int i = tid; i < BB * TT; i += NTHR) {
    int r = i / TT, tt = i % TT;
    labels_l[r][tt] = labels[(size_t)(r0 + r) * TT + tt];
  }
  for (int i = tid; i < BB * HSTR; i += NTHR) (&hpk_l[0][0])[i] = 0u;
  // pack the whole x sequence once: 8 rows x 192 t x 12 uints
  for (int i = tid; i < BB * TT * 12; i += NTHR) {
    int r = i / (TT * 12), rem = i % (TT * 12);
    int t = rem / 12, u = rem % 12;
    const float* p = train + ((size_t)(r0 + r) * TT + t) * INp + 2 * u;
    float2 v = *(const float2*)p;
    xpk_l[r][t * 12 + u] = cvt_pk_bf16(v.x, v.y);
  }

  // ---- persistent MFMA B-fragments (weights), 56 uints -> VGPRs ----
  // tile n covers gates [(w*2+n)*16, +16); lane supplies col=l15, k=grp*8+i
  uint4 wAf[2][3], wBf[2][4];
#pragma unroll
  for (int n = 0; n < 2; ++n) {
    const int gcol = (w * 2 + n) * 16 + l15;
    const unsigned* pa = wsA + (size_t)gcol * 48 + grp * 4;
    wAf[n][0] = *(const uint4*)(pa);
    wAf[n][1] = *(const uint4*)(pa + 16);
    wAf[n][2] = *(const uint4*)(pa + 32);
    const unsigned* pb = wsB + (size_t)gcol * 64 + grp * 4;
#pragma unroll
    for (int c = 0; c < 4; ++c) wBf[n][c] = *(const uint4*)(pb + c * 16);
  }

  // cell biases for unit `lane`
  const float bi0 = b_ih0[lane]       + b_hh0[lane];
  const float bf0 = b_ih0[64 + lane]  + b_hh0[64 + lane];
  const float bg0 = b_ih0[128 + lane] + b_hh0[128 + lane];
  const float bo0 = b_ih0[192 + lane] + b_hh0[192 + lane];
  const float bi1 = b_ih1[lane]       + b_hh1[lane];
  const float bf1 = b_ih1[64 + lane]  + b_hh1[64 + lane];
  const float bg1 = b_ih1[128 + lane] + b_hh1[128 + lane];
  const float bo1 = b_ih1[192 + lane] + b_hh1[192 + lane];
  float c0 = 0.0f, c1 = 0.0f;

  const float sig = 1.0f / (float)Kk;
  const int lcr = tid & 31;
  float myksi = 0.0f;
  for (int i = 0; i < lcr && i < Kk; ++i) myksi += sig;  // cumsum fidelity

  float cacc = 0.0f;

  // A-frag LDS pointers (loop-invariant except x advances by 12/step)
  const unsigned* a0x = &xpk_l[row_a][grp * 4];        // + t*12, for grp<3
  const unsigned* a0h = &hpk_l[row_a][0];              // grp==3: k 24-31 = h0[0..8)
  const unsigned* a1p = &hpk_l[row_a][4 + grp * 4];    // k 32-63 = h0[8..40)
  const unsigned* a2p = &hpk_l[row_a][20 + grp * 4];   // k 64-95 (grp3: pad, W=0)
  const unsigned* b0p = &hpk_l[row_a][grp * 4];        // L1 kc=0
  const unsigned* b1p = &hpk_l[row_a][16 + grp * 4];
  const unsigned* b2p = &hpk_l[row_a][32 + grp * 4];
  const unsigned* b3p = &hpk_l[row_a][48 + grp * 4];

  __syncthreads();

  for (int t = 0; t < TT; ++t) {
    // ======== G0: layer0 gates via MFMA ========
    {
      const unsigned* p0 = (grp < 3) ? (a0x + t * 12) : a0h;
      short8 A0 = as_bf(*(const uint4*)p0);
      short8 A1 = as_bf(*(const uint4*)a1p);
      short8 A2 = as_bf(*(const uint4*)a2p);
      f32x4 acc0 = {0.f, 0.f, 0.f, 0.f};
      f32x4 acc1 = {0.f, 0.f, 0.f, 0.f};
      acc0 = __builtin_amdgcn_mfma_f32_16x16x32_bf16(A0, as_bf(wAf[0][0]), acc0, 0, 0, 0);
      acc1 = __builtin_amdgcn_mfma_f32_16x16x32_bf16(A0, as_bf(wAf[1][0]), acc1, 0, 0, 0);
      acc0 = __builtin_amdgcn_mfma_f32_16x16x32_bf16(A1, as_bf(wAf[0][1]), acc0, 0, 0, 0);
      acc1 = __builtin_amdgcn_mfma_f32_16x16x32_bf16(A1, as_bf(wAf[1][1]), acc1, 0, 0, 0);
      acc0 = __builtin_amdgcn_mfma_f32_16x16x32_bf16(A2, as_bf(wAf[0][2]), acc0, 0, 0, 0);
      acc1 = __builtin_amdgcn_mfma_f32_16x16x32_bf16(A2, as_bf(wAf[1][2]), acc1, 0, 0, 0);
      if (lane < 32) {
        const int rb = (lane >> 4) * 4, cb = w * 32 + l15;
#pragma unroll
        for (int r = 0; r < 4; ++r) {
          gates_l[rb + r][cb]      = acc0[r];
          gates_l[rb + r][cb + 16] = acc1[r];
        }
      }
    }
    __syncthreads();  // B1

    // ======== cell L0 (all 512) + pack h0 ========
    {
      float gi_ = gates_l[w][lane]       + bi0;
      float gf_ = gates_l[w][64 + lane]  + bf0;
      float gg_ = gates_l[w][128 + lane] + bg0;
      float go_ = gates_l[w][192 + lane] + bo0;
      float cn = sigmoidf_(gf_) * c0 + sigmoidf_(gi_) * tanhf_(gg_);
      c0 = cn;
      float h = sigmoidf_(go_) * tanhf_(cn);
      bigh_l[w][lane] = h;
      float nb = __shfl_xor(h, 1, 64);
      unsigned pk = cvt_pk_bf16(h, nb);
      if ((lane & 1) == 0) hpk_l[w][lane >> 1] = pk;
    }
    __syncthreads();  // B2

    // ======== G1: layer1 gates via MFMA ========
    {
      short8 B0 = as_bf(*(const uint4*)b0p);
      short8 B1 = as_bf(*(const uint4*)b1p);
      short8 B2 = as_bf(*(const uint4*)b2p);
      short8 B3 = as_bf(*(const uint4*)b3p);
      f32x4 acc0 = {0.f, 0.f, 0.f, 0.f};
      f32x4 acc1 = {0.f, 0.f, 0.f, 0.f};
      acc0 = __builtin_amdgcn_mfma_f32_16x16x32_bf16(B0, as_bf(wBf[0][0]), acc0, 0, 0, 0);
      acc1 = __builtin_amdgcn_mfma_f32_16x16x32_bf16(B0, as_bf(wBf[1][0]), acc1, 0, 0, 0);
      acc0 = __builtin_amdgcn_mfma_f32_16x16x32_bf16(B1, as_bf(wBf[0][1]), acc0, 0, 0, 0);
      acc1 = __builtin_amdgcn_mfma_f32_16x16x32_bf16(B1, as_bf(wBf[1][1]), acc1, 0, 0, 0);
      acc0 = __builtin_amdgcn_mfma_f32_16x16x32_bf16(B2, as_bf(wBf[0][2]), acc0, 0, 0, 0);
      acc1 = __builtin_amdgcn_mfma_f32_16x16x32_bf16(B2, as_bf(wBf[1][2]), acc1, 0, 0, 0);
      acc0 = __builtin_amdgcn_mfma_f32_16x16x32_bf16(B3, as_bf(wBf[0][3]), acc0, 0, 0, 0);
      acc1 = __builtin_amdgcn_mfma_f32_16x16x32_bf16(B3, as_bf(wBf[1][3]), acc1, 0, 0, 0);
      if (lane < 32) {
        const int rb = (lane >> 4) * 4, cb = w * 32 + l15;
#pragma unroll
        for (int r = 0; r < 4; ++r) {
          gates_l[rb + r][cb]      = acc0[r];
          gates_l[rb + r][cb + 16] = acc1[r];
        }
      }
    }
    __syncthreads();  // B3

    // ======== fat phase (wave-local): cell1, proj, CRPS ========
    {
      float gi_ = gates_l[w][lane]       + bi1;
      float gf_ = gates_l[w][64 + lane]  + bf1;
      float gg_ = gates_l[w][128 + lane] + bg1;
      float go_ = gates_l[w][192 + lane] + bo1;
      float cn = sigmoidf_(gf_) * c1 + sigmoidf_(gi_) * tanhf_(gg_);
      c1 = cn;
      float h = sigmoidf_(go_) * tanhf_(cn);
      bigh_l[w][64 + lane] = h;
      float nb = __shfl_xor(h, 1, 64);
      unsigned pk = cvt_pk_bf16(h, nb);
      if ((lane & 1) == 0) hpk_l[w][32 + (lane >> 1)] = pk;
    }

    WAVE_LDS_FENCE();  // h0/h1 fp32+packed visible within wave

    // ---- projection + softplus: lanes 0..41 = (o, h-half) ----
    if (lane < 42) {
      const int o = lane >> 1, half = lane & 1;
      float lin = (half == 0) ? pbias[o] : 0.0f;
      const int hbeg = half * 32;
#pragma unroll 16
      for (int h = hbeg; h < hbeg + 32; ++h) {
        float2 wv2 = *(const float2*)&wproj[o][2 * h];
        lin += bigh_l[w][h] * wv2.x + bigh_l[w][64 + h] * wv2.y;
      }
      lin += __shfl_xor(lin, 1, 64);
      if (half == 0) wscr[w][o] = softplusf_(lin);
    }

    WAVE_LDS_FENCE();  // wscr visible

    // ---- CRPS (all lanes; 32-halves duplicate; lane 0 accumulates) ----
    {
      const int l = lcr;
      const bool valid = (l < Kk);
      const float y = labels_l[w][t];
      const float b0v = wscr[w][0];

      float braw = 0.0f;
      if (valid) {
        float gam = wscr[w][1 + l];
        float bp  = wscr[w][l];
        braw = (gam - bp) / (2.0f * sig);
      }
      float brawm1 = __shfl_up(braw, 1, 32);
      float bj = valid ? (braw - ((l == 0) ? 0.0f : brawm1)) : 0.0f;
      float st = (l < Kk - 1) ? bj : 0.0f;
#pragma unroll
      for (int off = 16; off > 0; off >>= 1) st += __shfl_xor(st, off, 32);
      if (l == Kk - 1) bj = wscr[w][Kk] - st;

      float knot = b0v * myksi;
      float kj = 0.0f;
#pragma unroll
      for (int j = 0; j < Kk; ++j) {
        float bjj = __shfl(bj, j, 32);
        float d = fmaxf(myksi - kj, 0.0f);
        knot += bjj * d * d;
        kj += sig;
      }
      float diff = y - knot;
      bool al = valid && (diff > 0.0f);
      float ab = al ? bj : 0.0f;
      float tA = ab;
      float tB = ab * myksi;
      float tC = ab * myksi * myksi;
      float u4 = 1.0f - myksi;
      float c3t = valid ? (bj * (1.0f / 6.0f)) * (u4 * u4 * u4 * u4) : 0.0f;
      float ad = valid ? fabsf(diff) : 3.4e38f;
      int ai = l;
#pragma unroll
      for (int off = 16; off > 0; off >>= 1) {
        tA += __shfl_xor(tA, off, 32);
        tB += __shfl_xor(tB, off, 32);
        tC += __shfl_xor(tC, off, 32);
        c3t += __shfl_xor(c3t, off, 32);
        float oad = __shfl_xor(ad, off, 32);
        int   oai = __shfl_xor(ai, off, 32);
        if (oad < ad || (oad == ad && oai < ai)) { ad = oad; ai = oai; }
      }
      float A   = tA;
      float Bco = b0v - 2.0f * tB;
      float Cc  = -y + tC;
      float disc = Bco * Bco - 4.0f * A * Cc;
      float ksi_pick = __shfl(myksi, ai, 32);
      float A_safe = (A != 0.0f) ? A : 1.0f;
      float B_safe = (Bco != 0.0f) ? Bco : 1.0f;
      float quad = (-Bco + sqrtf(fmaxf(disc, 0.0f))) / (2.0f * A_safe);
      float alpha = (A != 0.0f && disc >= 0.0f)
                        ? quad
                        : ((A == 0.0f) ? (-Cc / B_safe) : ksi_pick);
      float dk = alpha - myksi;
      float c4t = al ? ((2.0f / 3.0f) * bj) * (dk * dk * dk) : 0.0f;
#pragma unroll
      for (int off = 16; off > 0; off >>= 1) c4t += __shfl_xor(c4t, off, 32);
      float crps = y * (2.0f * alpha - 1.0f) +
                   b0v * ((1.0f / 3.0f) - alpha * alpha) + c3t - c4t;
      if (lane == 0) cacc += crps;
    }
    __syncthreads();  // B4
  }

  // ---- block reduction ----
  red_l[tid] = cacc;
  __syncthreads();
#pragma unroll
  for (int s = NTHR / 2; s > 0; s >>= 1) {
    if (tid < s) red_l[tid] += red_l[tid + s];
    __syncthreads();
  }
  if (tid == 0) partials[blockIdx.x] = red_l[0];
}

__global__ void final_reduce_kernel(const float* __restrict__ partials,
                                    float* __restrict__ out) {
  __shared__ float s_l[NBLK];
  const int tid = (int)threadIdx.x;
  s_l[tid] = partials[tid];
  __syncthreads();
  for (int s = NBLK / 2; s > 0; s >>= 1) {
    if (tid < s) s_l[tid] += s_l[tid + s];
    __syncthreads();
  }
  if (tid == 0) out[0] = s_l[0] * (1.0f / 2048.0f);
}

}  // namespace

extern "C" void kernel_launch(void* const* d_in, const int* in_sizes, int n_in,
                              void* d_out, int out_size, void* d_ws, size_t ws_size,
                              hipStream_t stream) {
  (void)in_sizes; (void)n_in; (void)out_size; (void)ws_size;
  const float* train  = (const float*)d_in[0];
  const float* labels = (const float*)d_in[1];
  const float* w_ih0  = (const float*)d_in[2];
  const float* w_hh0  = (const float*)d_in[3];
  const float* b_ih0  = (const float*)d_in[4];
  const float* b_hh0  = (const float*)d_in[5];
  const float* w_ih1  = (const float*)d_in[6];
  const float* w_hh1  = (const float*)d_in[7];
  const float* b_ih1  = (const float*)d_in[8];
  const float* b_hh1  = (const float*)d_in[9];
  const float* w_b0   = (const float*)d_in[10];
  const float* bb_b0  = (const float*)d_in[11];
  const float* w_g    = (const float*)d_in[12];
  const float* b_g    = (const float*)d_in[13];

  unsigned* wsA = (unsigned*)d_ws;
  unsigned* wsB = wsA + WSA_U;
  float* partials = (float*)((char*)d_ws + (size_t)NWU * 4);

  wconv_kernel<<<dim3((NWU + 255) / 256), dim3(256), 0, stream>>>(
      w_ih0, w_hh0, w_ih1, w_hh1, wsA);
  lstm_crps_kernel<<<dim3(NBLK), dim3(NTHR), 0, stream>>>(
      train, labels, b_ih0, b_hh0, b_ih1, b_hh1,
      w_b0, bb_b0, w_g, b_g, wsA, wsB, partials);
  final_reduce_kernel<<<dim3(1), dim3(NBLK), 0, stream>>>(partials,
                                                          (float*)d_out);
}

// Round 9
// 315.169 us; speedup vs baseline: 22.8976x; 2.6146x over previous
//
#include <hip/hip_runtime.h>
#include <math.h>

namespace {

constexpr int TT  = 192;
constexpr int INp = 24;
constexpr int Kk  = 20;
constexpr int BB  = 8;            // batch rows per block (= waves)
constexpr int NTHR = 512;         // 8 waves

constexpr int XSTR = 2308;        // xpk row stride (uints)
constexpr int HP   = 36;          // hpk row stride (uints): 32 data + 4 zero pad
constexpr int GS   = 33;          // gscr row stride (floats, odd -> bank spread)

// workspace layout (bytes)
constexpr int WSA_U = 256 * 48;   // L0 weights, interleaved cols, packed bf16
constexpr int WSB_U = 256 * 64;   // L1 weights
constexpr int WP_U  = 21 * 64;    // proj weights packed for dot2
constexpr int WTOT  = WSA_U + WSB_U + WP_U;
constexpr size_t OFF_WSB  = 49152;
constexpr size_t OFF_WP   = 114688;
constexpr size_t OFF_PART = 120832;
constexpr size_t OFF_HIST = 131072;
constexpr size_t ROW_BYTES = (size_t)TT * 64 * 4;   // hist bytes per batch row

using short8 = __attribute__((ext_vector_type(8))) short;  // 8 bf16
using f32x4  = __attribute__((ext_vector_type(4))) float;

__device__ __forceinline__ float sigmoidf_(float x) {
  return 1.0f / (1.0f + __expf(-x));
}
__device__ __forceinline__ float tanhf_(float x) {
  return 2.0f / (1.0f + __expf(-2.0f * x)) - 1.0f;
}
__device__ __forceinline__ float softplusf_(float x) {
  return fmaxf(x, 0.0f) + log1pf(__expf(-fabsf(x)));
}
__device__ __forceinline__ unsigned cvt_pk_bf16(float a, float b) {
  unsigned r;
  asm("v_cvt_pk_bf16_f32 %0, %1, %2" : "=v"(r) : "v"(a), "v"(b));
  return r;
}
__device__ __forceinline__ unsigned bf16rne(float x) {
  unsigned u = __float_as_uint(x);
  return (u + 0x7FFFu + ((u >> 16) & 1u)) >> 16;
}
__device__ __forceinline__ short8 as_bf(uint4 u) {
  short8 s; __builtin_memcpy(&s, &u, 16); return s;
}
#define DOT2(acc, wv, vv) \
  asm("v_dot2_f32_bf16 %0, %1, %2, %0" : "+v"(acc) : "v"(wv), "v"(vv))

#define WAVE_LDS_FENCE()                                  \
  do {                                                    \
    asm volatile("s_waitcnt lgkmcnt(0)" ::: "memory");    \
    __builtin_amdgcn_sched_barrier(0);                    \
  } while (0)

// ---- weight prep: bf16-pack LSTM weights in GATE-INTERLEAVED column order
// (col g = feat*4 + q, orig row = q*64 + feat) + pack proj weights for dot2.
__global__ void wconv_kernel(const float* __restrict__ w_ih0,
                             const float* __restrict__ w_hh0,
                             const float* __restrict__ w_ih1,
                             const float* __restrict__ w_hh1,
                             const float* __restrict__ w_b0,
                             const float* __restrict__ w_g,
                             unsigned* __restrict__ wsA,
                             unsigned* __restrict__ wsB,
                             unsigned* __restrict__ wp) {
  int i = (int)(blockIdx.x * 256 + threadIdx.x);
  if (i >= WTOT) return;
  float lo = 0.f, hi = 0.f;
  if (i < WSA_U) {
    int g = i / 48, j = i % 48;
    int orig = (g & 3) * 64 + (g >> 2);
    if (j < 12)      { lo = w_ih0[orig * 24 + 2 * j]; hi = w_ih0[orig * 24 + 2 * j + 1]; }
    else if (j < 44) { lo = w_hh0[orig * 64 + 2 * (j - 12)]; hi = w_hh0[orig * 64 + 2 * (j - 12) + 1]; }
    wsA[i] = bf16rne(lo) | (bf16rne(hi) << 16);
  } else if (i < WSA_U + WSB_U) {
    int i2 = i - WSA_U;
    int g = i2 / 64, j = i2 % 64;
    int orig = (g & 3) * 64 + (g >> 2);
    if (j < 32) { lo = w_ih1[orig * 64 + 2 * j]; hi = w_ih1[orig * 64 + 2 * j + 1]; }
    else        { lo = w_hh1[orig * 64 + 2 * (j - 32)]; hi = w_hh1[orig * 64 + 2 * (j - 32) + 1]; }
    wsB[i2] = bf16rne(lo) | (bf16rne(hi) << 16);
  } else {
    int i3 = i - WSA_U - WSB_U;
    int o = i3 >> 6, j = i3 & 63;
    const float* row = (o == 0) ? w_b0 : (w_g + (size_t)(o - 1) * 128);
    if (j < 32) { lo = row[4 * j];            hi = row[4 * j + 2]; }
    else        { lo = row[4 * (j - 32) + 1]; hi = row[4 * (j - 32) + 3]; }
    wp[i3] = bf16rne(lo) | (bf16rne(hi) << 16);
  }
}

// ======== kernel 1: pure LSTM recurrence, hist(h0,h1 bf16-packed) -> global
__global__ __launch_bounds__(NTHR, 1) void lstm_kernel(
    const float* __restrict__ train,   // [2048,192,24]
    const float* __restrict__ b_ih0, const float* __restrict__ b_hh0,
    const float* __restrict__ b_ih1, const float* __restrict__ b_hh1,
    const unsigned* __restrict__ wsA,  // [256][48] interleaved
    const unsigned* __restrict__ wsB,  // [256][64] interleaved
    unsigned* __restrict__ hist,       // [chunk_rows][192][64]
    int rb)
{
  __shared__ __align__(16) unsigned xpk_l[BB][XSTR];
  __shared__ __align__(16) unsigned hpk0_l[2][BB][HP];  // h0, double-buffered
  __shared__ __align__(16) unsigned hpk1_l[2][BB][HP];  // h1, double-buffered
  __shared__ float gscr_l[8][BB][GS];                   // per-wave gate scratch

  const int tid   = (int)threadIdx.x;
  const int lane  = tid & 63;
  const int w     = tid >> 6;      // wave
  const int l15   = lane & 15;
  const int grp   = lane >> 4;     // MFMA k-group 0..3
  const int row_a = lane & 7;      // A-frag source row (8-15 dup)
  const int crow  = lane & 7;      // cell: batch row
  const int cfl   = lane >> 3;     // cell: local feature 0..7
  const int feat  = w * 8 + cfl;   // global feature 0..63
  const int r0g   = rb + (int)blockIdx.x * BB;

  // ---- stage packed x once ----
  for (int i = tid; i < BB * TT * 12; i += NTHR) {
    int r = i / (TT * 12), rem = i % (TT * 12);
    int t = rem / 12, u = rem % 12;
    const float* p = train + ((size_t)(r0g + r) * TT + t) * INp + 2 * u;
    float2 v = *(const float2*)p;
    xpk_l[r][t * 12 + u] = cvt_pk_bf16(v.x, v.y);
  }
  for (int i = tid; i < 2 * BB * HP; i += NTHR) {
    (&hpk0_l[0][0][0])[i] = 0u;
    (&hpk1_l[0][0][0])[i] = 0u;
  }

  // ---- persistent MFMA B-frags (weights): 56 uints in VGPRs ----
  uint4 wAf[2][3], wBf[2][4];
#pragma unroll
  for (int n = 0; n < 2; ++n) {
    const int gcol = w * 32 + n * 16 + l15;   // interleaved gate col
    const unsigned* pa = wsA + (size_t)gcol * 48 + grp * 4;
    wAf[n][0] = *(const uint4*)(pa);
    wAf[n][1] = *(const uint4*)(pa + 16);
    wAf[n][2] = *(const uint4*)(pa + 32);
    const unsigned* pb = wsB + (size_t)gcol * 64 + grp * 4;
#pragma unroll
    for (int c = 0; c < 4; ++c) wBf[n][c] = *(const uint4*)(pb + c * 16);
  }

  // ---- per-lane cell biases (q = i,f,g,o) ----
  float bq0[4], bq1[4];
#pragma unroll
  for (int q = 0; q < 4; ++q) {
    bq0[q] = b_ih0[q * 64 + feat] + b_hh0[q * 64 + feat];
    bq1[q] = b_ih1[q * 64 + feat] + b_hh1[q * 64 + feat];
  }
  float c0 = 0.0f, c1 = 0.0f;

  unsigned* histp = hist + (size_t)((size_t)blockIdx.x * BB + crow) * TT * 64;
  const int j0 = w * 4 + (cfl >> 1);
  const bool writer = ((cfl & 1) == 0);

  __syncthreads();

  for (int t = 0; t < TT; ++t) {
    const int wp_ = t & 1, rp_ = wp_ ^ 1;

    // ======== G0 (reads x(t), h0(t-1)=hpk0[rp_]) ========
    {
      const unsigned* p0 = (grp < 3) ? &xpk_l[row_a][t * 12 + grp * 4]
                                     : &hpk0_l[rp_][row_a][0];
      short8 A0 = as_bf(*(const uint4*)p0);
      short8 A1 = as_bf(*(const uint4*)&hpk0_l[rp_][row_a][4 + grp * 4]);
      short8 A2 = as_bf(*(const uint4*)&hpk0_l[rp_][row_a][20 + grp * 4]);
      f32x4 acc0 = {0.f, 0.f, 0.f, 0.f};
      f32x4 acc1 = {0.f, 0.f, 0.f, 0.f};
      acc0 = __builtin_amdgcn_mfma_f32_16x16x32_bf16(A0, as_bf(wAf[0][0]), acc0, 0, 0, 0);
      acc1 = __builtin_amdgcn_mfma_f32_16x16x32_bf16(A0, as_bf(wAf[1][0]), acc1, 0, 0, 0);
      acc0 = __builtin_amdgcn_mfma_f32_16x16x32_bf16(A1, as_bf(wAf[0][1]), acc0, 0, 0, 0);
      acc1 = __builtin_amdgcn_mfma_f32_16x16x32_bf16(A1, as_bf(wAf[1][1]), acc1, 0, 0, 0);
      acc0 = __builtin_amdgcn_mfma_f32_16x16x32_bf16(A2, as_bf(wAf[0][2]), acc0, 0, 0, 0);
      acc1 = __builtin_amdgcn_mfma_f32_16x16x32_bf16(A2, as_bf(wAf[1][2]), acc1, 0, 0, 0);
      if (lane < 32) {
        const int rbse = (lane >> 4) * 4;
#pragma unroll
        for (int r = 0; r < 4; ++r) {
          gscr_l[w][rbse + r][l15]      = acc0[r];
          gscr_l[w][rbse + r][l15 + 16] = acc1[r];
        }
      }
    }
    WAVE_LDS_FENCE();
    // cell L0 (wave-local): lane owns (crow, feat)
    {
      float gi_ = gscr_l[w][crow][cfl * 4 + 0] + bq0[0];
      float gf_ = gscr_l[w][crow][cfl * 4 + 1] + bq0[1];
      float gg_ = gscr_l[w][crow][cfl * 4 + 2] + bq0[2];
      float go_ = gscr_l[w][crow][cfl * 4 + 3] + bq0[3];
      float cn = sigmoidf_(gf_) * c0 + sigmoidf_(gi_) * tanhf_(gg_);
      c0 = cn;
      float h0v = sigmoidf_(go_) * tanhf_(cn);
      float hpart = __shfl_xor(h0v, 8, 64);
      if (writer) {
        unsigned pk = cvt_pk_bf16(h0v, hpart);
        hpk0_l[wp_][crow][j0] = pk;
        histp[(size_t)t * 64 + j0] = pk;
      }
    }
    __syncthreads();  // the ONLY block barrier per step

    // ======== G1 (reads h0(t)=hpk0[wp_], h1(t-1)=hpk1[rp_]) ========
    {
      short8 B0 = as_bf(*(const uint4*)&hpk0_l[wp_][row_a][grp * 4]);
      short8 B1v = as_bf(*(const uint4*)&hpk0_l[wp_][row_a][16 + grp * 4]);
      short8 B2v = as_bf(*(const uint4*)&hpk1_l[rp_][row_a][grp * 4]);
      short8 B3v = as_bf(*(const uint4*)&hpk1_l[rp_][row_a][16 + grp * 4]);
      f32x4 acc0 = {0.f, 0.f, 0.f, 0.f};
      f32x4 acc1 = {0.f, 0.f, 0.f, 0.f};
      acc0 = __builtin_amdgcn_mfma_f32_16x16x32_bf16(B0, as_bf(wBf[0][0]), acc0, 0, 0, 0);
      acc1 = __builtin_amdgcn_mfma_f32_16x16x32_bf16(B0, as_bf(wBf[1][0]), acc1, 0, 0, 0);
      acc0 = __builtin_amdgcn_mfma_f32_16x16x32_bf16(B1v, as_bf(wBf[0][1]), acc0, 0, 0, 0);
      acc1 = __builtin_amdgcn_mfma_f32_16x16x32_bf16(B1v, as_bf(wBf[1][1]), acc1, 0, 0, 0);
      acc0 = __builtin_amdgcn_mfma_f32_16x16x32_bf16(B2v, as_bf(wBf[0][2]), acc0, 0, 0, 0);
      acc1 = __builtin_amdgcn_mfma_f32_16x16x32_bf16(B2v, as_bf(wBf[1][2]), acc1, 0, 0, 0);
      acc0 = __builtin_amdgcn_mfma_f32_16x16x32_bf16(B3v, as_bf(wBf[0][3]), acc0, 0, 0, 0);
      acc1 = __builtin_amdgcn_mfma_f32_16x16x32_bf16(B3v, as_bf(wBf[1][3]), acc1, 0, 0, 0);
      if (lane < 32) {
        const int rbse = (lane >> 4) * 4;
#pragma unroll
        for (int r = 0; r < 4; ++r) {
          gscr_l[w][rbse + r][l15]      = acc0[r];
          gscr_l[w][rbse + r][l15 + 16] = acc1[r];
        }
      }
    }
    WAVE_LDS_FENCE();
    // cell L1 (wave-local)
    {
      float gi_ = gscr_l[w][crow][cfl * 4 + 0] + bq1[0];
      float gf_ = gscr_l[w][crow][cfl * 4 + 1] + bq1[1];
      float gg_ = gscr_l[w][crow][cfl * 4 + 2] + bq1[2];
      float go_ = gscr_l[w][crow][cfl * 4 + 3] + bq1[3];
      float cn = sigmoidf_(gf_) * c1 + sigmoidf_(gi_) * tanhf_(gg_);
      c1 = cn;
      float h1v = sigmoidf_(go_) * tanhf_(cn);
      float hpart = __shfl_xor(h1v, 8, 64);
      if (writer) {
        unsigned pk = cvt_pk_bf16(h1v, hpart);
        hpk1_l[wp_][crow][j0] = pk;
        histp[(size_t)t * 64 + 32 + j0] = pk;
      }
    }
    // no trailing barrier: next G0 reads hpk0[wp_] (barrier'd at B1 above);
    // cell0(t+1) writes hpk0[rp_] whose last readers were pre-B1(t). All
    // cross-wave producer/consumer pairs are >=1 barrier apart (see analysis).
  }
}

// ======== kernel 2: proj + softplus + CRPS, one lane per (b,t) task
__global__ __launch_bounds__(192, 2) void crps_kernel(
    const unsigned* __restrict__ hist,  // [chunk_rows][192][64]
    const float* __restrict__ labels,   // [2048][192]
    const unsigned* __restrict__ wp,    // [21][64]
    const float* __restrict__ bb_b0,
    const float* __restrict__ b_g,
    float* __restrict__ partials,       // [2048]
    int rb)
{
  __shared__ unsigned wp_l[21][64];
  __shared__ float pb_l[21];
  __shared__ float rw_l[3];

  const int tid = (int)threadIdx.x;       // == t
  const int bloc = (int)blockIdx.x;
  const int bglob = rb + bloc;
  const float sig = 1.0f / (float)Kk;

  for (int i = tid; i < 21 * 64; i += 192) wp_l[i >> 6][i & 63] = wp[i];
  if (tid < 21) pb_l[tid] = (tid == 0) ? bb_b0[0] : b_g[tid - 1];
  __syncthreads();

  // hist row for this task
  uint4 hh[16];
  const uint4* hp4 = (const uint4*)(hist + ((size_t)bloc * TT + tid) * 64);
#pragma unroll
  for (int c = 0; c < 16; ++c) hh[c] = hp4[c];
  const float y = labels[(size_t)bglob * TT + tid];

  // ---- projection + softplus (bg[0]=beta0, bg[1..20]=gamma) ----
  float bg[21];
#pragma unroll
  for (int o = 0; o < 21; ++o) {
    float lin = pb_l[o];
#pragma unroll
    for (int c = 0; c < 16; ++c) {
      uint4 wv = *(const uint4*)&wp_l[o][c * 4];
      DOT2(lin, wv.x, hh[c].x);
      DOT2(lin, wv.y, hh[c].y);
      DOT2(lin, wv.z, hh[c].z);
      DOT2(lin, wv.w, hh[c].w);
    }
    bg[o] = softplusf_(lin);
  }

  // ---- CRPS (scalar per lane) ----
  float braw[Kk], bj[Kk], ksi[Kk];
  {
    float kv = 0.0f;
#pragma unroll
    for (int l = 0; l < Kk; ++l) { ksi[l] = kv; kv += sig; }
  }
#pragma unroll
  for (int l = 0; l < Kk; ++l) {
    float bp = (l == 0) ? bg[0] : bg[l];
    braw[l] = (bg[l + 1] - bp) / (2.0f * sig);
  }
#pragma unroll
  for (int l = 0; l < Kk; ++l)
    bj[l] = braw[l] - ((l == 0) ? 0.0f : braw[l - 1]);
  {
    float st = 0.0f;
#pragma unroll
    for (int l = 0; l < Kk - 1; ++l) st += bj[l];
    bj[Kk - 1] = bg[Kk] - st;
  }

  float A = 0.f, tB = 0.f, tC = 0.f, c3a = 0.f;
  float ab[Kk];
  float ad = 3.4e38f, kpick = 0.f;
#pragma unroll
  for (int i = 0; i < Kk; ++i) {
    float kn = bg[0] * ksi[i];
#pragma unroll
    for (int j = 0; j < Kk; ++j) {
      if (j < i) {
        float d = ksi[i] - ksi[j];
        kn = fmaf(bj[j] * d, d, kn);
      }
    }
    float diff = y - kn;
    float abv = (diff > 0.0f) ? bj[i] : 0.0f;
    ab[i] = abv;
    A += abv;
    tB = fmaf(abv, ksi[i], tB);
    tC = fmaf(abv * ksi[i], ksi[i], tC);
    float um = 1.0f - ksi[i], um2 = um * um;
    c3a = fmaf(bj[i] * (1.0f / 6.0f), um2 * um2, c3a);
    float adi = fabsf(diff);
    if (adi < ad) { ad = adi; kpick = ksi[i]; }
  }
  float Bq = bg[0] - 2.0f * tB;
  float Cc = -y + tC;
  float disc = Bq * Bq - 4.0f * A * Cc;
  float A_safe = (A != 0.0f) ? A : 1.0f;
  float B_safe = (Bq != 0.0f) ? Bq : 1.0f;
  float quad = (-Bq + sqrtf(fmaxf(disc, 0.0f))) / (2.0f * A_safe);
  float alpha = (A != 0.0f && disc >= 0.0f)
                    ? quad
                    : ((A == 0.0f) ? (-Cc / B_safe) : kpick);
  float c4 = 0.0f;
#pragma unroll
  for (int i = 0; i < Kk; ++i) {
    float d = alpha - ksi[i];
    c4 = fmaf(ab[i] * (2.0f / 3.0f), d * d * d, c4);
  }
  float crps = y * (2.0f * alpha - 1.0f) +
               bg[0] * ((1.0f / 3.0f) - alpha * alpha) + c3a - c4;

  // ---- block reduce (3 waves) ----
  float v = crps;
#pragma unroll
  for (int off = 32; off > 0; off >>= 1) v += __shfl_xor(v, off, 64);
  if ((tid & 63) == 0) rw_l[tid >> 6] = v;
  __syncthreads();
  if (tid == 0) partials[bglob] = rw_l[0] + rw_l[1] + rw_l[2];
}

__global__ void final_reduce_kernel(const float* __restrict__ partials,
                                    float* __restrict__ out) {
  __shared__ float s_l[1024];
  const int tid = (int)threadIdx.x;
  s_l[tid] = partials[tid] + partials[tid + 1024];
  __syncthreads();
  for (int s = 512; s > 0; s >>= 1) {
    if (tid < s) s_l[tid] += s_l[tid + s];
    __syncthreads();
  }
  if (tid == 0) out[0] = s_l[0] * (1.0f / 2048.0f);
}

}  // namespace

extern "C" void kernel_launch(void* const* d_in, const int* in_sizes, int n_in,
                              void* d_out, int out_size, void* d_ws, size_t ws_size,
                              hipStream_t stream) {
  (void)in_sizes; (void)n_in; (void)out_size;
  const float* train  = (const float*)d_in[0];
  const float* labels = (const float*)d_in[1];
  const float* w_ih0  = (const float*)d_in[2];
  const float* w_hh0  = (const float*)d_in[3];
  const float* b_ih0  = (const float*)d_in[4];
  const float* b_hh0  = (const float*)d_in[5];
  const float* w_ih1  = (const float*)d_in[6];
  const float* w_hh1  = (const float*)d_in[7];
  const float* b_ih1  = (const float*)d_in[8];
  const float* b_hh1  = (const float*)d_in[9];
  const float* w_b0   = (const float*)d_in[10];
  const float* bb_b0  = (const float*)d_in[11];
  const float* w_g    = (const float*)d_in[12];
  const float* b_g    = (const float*)d_in[13];

  unsigned* wsA   = (unsigned*)d_ws;
  unsigned* wsB   = (unsigned*)((char*)d_ws + OFF_WSB);
  unsigned* wp    = (unsigned*)((char*)d_ws + OFF_WP);
  float* partials = (float*)((char*)d_ws + OFF_PART);
  unsigned* hist  = (unsigned*)((char*)d_ws + OFF_HIST);

  // hist chunking if ws is small (single pass when ws >= ~101 MB)
  size_t avail = (ws_size > OFF_HIST) ? (ws_size - OFF_HIST) : 0;
  size_t rows_fit = avail / ROW_BYTES;
  int chunk = (rows_fit >= 2048) ? 2048 : (int)rows_fit;
  chunk &= ~7;
  if (chunk < 8) chunk = 8;

  wconv_kernel<<<dim3((WTOT + 255) / 256), dim3(256), 0, stream>>>(
      w_ih0, w_hh0, w_ih1, w_hh1, w_b0, w_g, wsA, wsB, wp);

  for (int rb = 0; rb < 2048; rb += chunk) {
    int cur = (2048 - rb < chunk) ? (2048 - rb) : chunk;
    lstm_kernel<<<dim3(cur / 8), dim3(NTHR), 0, stream>>>(
        train, b_ih0, b_hh0, b_ih1, b_hh1, wsA, wsB, hist, rb);
    crps_kernel<<<dim3(cur), dim3(192), 0, stream>>>(
        hist, labels, wp, bb_b0, b_g, partials, rb);
  }
  final_reduce_kernel<<<dim3(1), dim3(1024), 0, stream>>>(partials,
                                                          (float*)d_out);
}